// Round 1
// baseline (303.663 us; speedup 1.0000x reference)
//
#include <hip/hip_runtime.h>
#include <math.h>

#define PI_F 3.14159265358979323846f

// ---------- complex helpers ----------
struct Cx { float re, im; };
__device__ __forceinline__ Cx cmul(Cx a, Cx b) {
    return { a.re * b.re - a.im * b.im, a.re * b.im + a.im * b.re };
}
__device__ __forceinline__ Cx cadd(Cx a, Cx b) { return { a.re + b.re, a.im + b.im }; }

struct M2 { Cx m[2][2]; };

__device__ __forceinline__ M2 mmul(const M2& A, const M2& B) {
    M2 R;
    for (int i = 0; i < 2; i++)
        for (int j = 0; j < 2; j++)
            R.m[i][j] = cadd(cmul(A.m[i][0], B.m[0][j]), cmul(A.m[i][1], B.m[1][j]));
    return R;
}
__device__ __forceinline__ M2 mry(float t) {
    float c = cosf(0.5f * t), s = sinf(0.5f * t);
    M2 R; R.m[0][0] = {c, 0}; R.m[0][1] = {-s, 0}; R.m[1][0] = {s, 0}; R.m[1][1] = {c, 0};
    return R;
}
__device__ __forceinline__ M2 mrz(float t) {
    float c = cosf(0.5f * t), s = sinf(0.5f * t);
    M2 R; R.m[0][0] = {c, -s}; R.m[0][1] = {0, 0}; R.m[1][0] = {0, 0}; R.m[1][1] = {c, s};
    return R;
}
__device__ __forceinline__ M2 mrx(float t) {
    float c = cosf(0.5f * t), s = sinf(0.5f * t);
    M2 R; R.m[0][0] = {c, 0}; R.m[0][1] = {0, -s}; R.m[1][0] = {0, -s}; R.m[1][1] = {c, 0};
    return R;
}
// Rot(phi, theta, omega) = RZ(omega) @ RY(theta) @ RZ(phi)
__device__ __forceinline__ M2 mrot(float phi, float th, float om) {
    return mmul(mmul(mrz(om), mry(th)), mrz(phi));
}

// ---------- gate application on LDS statevector (9 wires, 512 amps) ----------
// wire w -> bit (8 - w): wire 0 is the most significant bit of the flat index.

__device__ __forceinline__ void apply1(float2* st, const M2& U, int wire, int lane) {
    int bit = 8 - wire;
    int low = (1 << bit) - 1;
    for (int k = lane; k < 256; k += 64) {
        int i0 = ((k & ~low) << 1) | (k & low);
        int i1 = i0 | (1 << bit);
        float2 a = st[i0], b = st[i1];
        float2 na, nb;
        na.x = U.m[0][0].re * a.x - U.m[0][0].im * a.y + U.m[0][1].re * b.x - U.m[0][1].im * b.y;
        na.y = U.m[0][0].re * a.y + U.m[0][0].im * a.x + U.m[0][1].re * b.y + U.m[0][1].im * b.x;
        nb.x = U.m[1][0].re * a.x - U.m[1][0].im * a.y + U.m[1][1].re * b.x - U.m[1][1].im * b.y;
        nb.y = U.m[1][0].re * a.y + U.m[1][0].im * a.x + U.m[1][1].re * b.y + U.m[1][1].im * b.x;
        st[i0] = na; st[i1] = nb;
    }
    __syncthreads();
}

// index with control bit set, target bit clear; k enumerates the other 7 bits
__device__ __forceinline__ int idx_c1t0(int k, int cbit, int tbit) {
    int lo = cbit < tbit ? cbit : tbit;
    int hi = cbit < tbit ? tbit : cbit;
    int mlo = (1 << lo) - 1, mhi = (1 << hi) - 1;
    int i = ((k & ~mlo) << 1) | (k & mlo);   // insert 0 at lo
    i = ((i & ~mhi) << 1) | (i & mhi);       // insert 0 at hi
    return i | (1 << cbit);
}

// controlled-U: control wire cw, target wire tw
__device__ __forceinline__ void applyc(float2* st, const M2& U, int cw, int tw, int lane) {
    int cbit = 8 - cw, tbit = 8 - tw;
    for (int k = lane; k < 128; k += 64) {
        int i0 = idx_c1t0(k, cbit, tbit);
        int i1 = i0 | (1 << tbit);
        float2 a = st[i0], b = st[i1];
        float2 na, nb;
        na.x = U.m[0][0].re * a.x - U.m[0][0].im * a.y + U.m[0][1].re * b.x - U.m[0][1].im * b.y;
        na.y = U.m[0][0].re * a.y + U.m[0][0].im * a.x + U.m[0][1].re * b.y + U.m[0][1].im * b.x;
        nb.x = U.m[1][0].re * a.x - U.m[1][0].im * a.y + U.m[1][1].re * b.x - U.m[1][1].im * b.y;
        nb.y = U.m[1][0].re * a.y + U.m[1][0].im * a.x + U.m[1][1].re * b.y + U.m[1][1].im * b.x;
        st[i0] = na; st[i1] = nb;
    }
    __syncthreads();
}

__device__ __forceinline__ void cnot(float2* st, int cw, int tw, int lane) {
    int cbit = 8 - cw, tbit = 8 - tw;
    for (int k = lane; k < 128; k += 64) {
        int i0 = idx_c1t0(k, cbit, tbit);
        int i1 = i0 | (1 << tbit);
        float2 a = st[i0];
        st[i0] = st[i1];
        st[i1] = a;
    }
    __syncthreads();
}

// StronglyEntanglingLayers, L=1, 3 wires: Rot on each wire then CNOT ring (r=1)
__device__ __forceinline__ void sel3(float2* st, const float* w, int w0, int w1, int w2, int lane) {
    int wires[3] = { w0, w1, w2 };
    for (int j = 0; j < 3; j++) {
        M2 U = mrot(w[j * 3 + 0], w[j * 3 + 1], w[j * 3 + 2]);
        apply1(st, U, wires[j], lane);
    }
    for (int j = 0; j < 3; j++) cnot(st, wires[j], wires[(j + 1) % 3], lane);
}

// ---------- kernels ----------

// tanh(mlp(feat)) * pi, IN_DIM -> 128 -> 2, one thread per row
template <int IN_DIM>
__global__ void mlp_tanh_kernel(const float* __restrict__ feat, const float* __restrict__ W1,
                                const float* __restrict__ b1, const float* __restrict__ W2,
                                const float* __restrict__ b2, float* __restrict__ out, int rows) {
    int r = blockIdx.x * blockDim.x + threadIdx.x;
    if (r >= rows) return;
    float f[IN_DIM];
#pragma unroll
    for (int k = 0; k < IN_DIM; k++) f[k] = feat[r * IN_DIM + k];
    float o0 = b2[0], o1 = b2[1];
    for (int j = 0; j < 128; j++) {
        float h = b1[j];
#pragma unroll
        for (int k = 0; k < IN_DIM; k++) h += f[k] * W1[k * 128 + j];
        h = h > 0.f ? h : 0.01f * h;   // leaky_relu, slope 0.01
        o0 += h * W2[j * 2 + 0];
        o1 += h * W2[j * 2 + 1];
    }
    out[r * 2 + 0] = tanhf(o0) * PI_F;
    out[r * 2 + 1] = tanhf(o1) * PI_F;
}

// one 64-thread block per sample; full 512-amp statevector in LDS
__global__ __launch_bounds__(64) void pqc_kernel(
        const float* __restrict__ x, const float* __restrict__ e,
        const int* __restrict__ subgraphs, const int* __restrict__ edge_ids,
        const float* __restrict__ strong, const float* __restrict__ inits,
        const float* __restrict__ update, float* __restrict__ aggr) {
    __shared__ float2 st[512];
    int s = blockIdx.x;
    int lane = threadIdx.x;

    for (int k = lane; k < 512; k += 64) st[k] = make_float2(0.f, 0.f);
    __syncthreads();
    if (lane == 0) st[0] = make_float2(1.f, 0.f);
    __syncthreads();

    // q_in: rows 0..2 = e[edge_ids[s]], rows 3..6 = x[subgraphs[s]]
    float ang[7][2];
    for (int j = 0; j < 3; j++) {
        int eid = edge_ids[s * 3 + j];
        ang[j][0] = e[2 * eid]; ang[j][1] = e[2 * eid + 1];
    }
    for (int j = 0; j < 4; j++) {
        int nid = subgraphs[s * 4 + j];
        ang[3 + j][0] = x[2 * nid]; ang[3 + j][1] = x[2 * nid + 1];
    }

    // encoding layer
    for (int i = 0; i < 3; i++) {
        apply1(st, mry(ang[i][0]), i, lane);
        apply1(st, mrz(ang[i][1]), i, lane);
    }
    for (int i = 0; i < 4; i++) {
        apply1(st, mry(ang[3 + i][0]), 3 + i, lane);
        apply1(st, mrz(ang[3 + i][1]), 3 + i, lane);
    }

    float v0 = inits[0], v1 = inits[1], v2 = inits[2], v3 = inits[3];
    M2 crx = mrx(v0), cry1 = mry(v1), crz = mrz(v2), cry2 = mry(v3);
    for (int i = 0; i < 3; i++) {
        int ew = i, nb = 4 + i, a1 = 7, a2 = 8;
        applyc(st, crx, nb, a1, lane);
        applyc(st, cry1, ew, a1, lane);
        applyc(st, crz, nb, a2, lane);
        applyc(st, cry2, ew, a2, lane);
        sel3(st, strong, ew, nb, a1, lane);       // strong[0]
        sel3(st, strong + 9, a1, nb, a2, lane);   // strong[1]
    }
    sel3(st, update, 3, 7, 8, lane);

    // <X_3>: wire 3 -> bit 5 (value 32); 2*Re(conj(z0)*z1) over the 8x32 other dims
    float acc = 0.f;
    for (int k = lane; k < 256; k += 64) {
        int a = k >> 5, b = k & 31;
        int j0 = (a << 6) | b;
        int j1 = j0 | 32;
        float2 z0 = st[j0], z1 = st[j1];
        acc += z0.x * z1.x + z0.y * z1.y;
    }
    acc *= 2.f;
    for (int off = 32; off > 0; off >>= 1) acc += __shfl_down(acc, off);
    if (lane == 0) aggr[s] = acc;
}

// upd = mlp([x[center], aggr], 3->128->2); scatter-add into xadd at center
__global__ void upd_kernel(const float* __restrict__ x, const float* __restrict__ aggr,
                           const int* __restrict__ subgraphs,
                           const float* __restrict__ W1, const float* __restrict__ b1,
                           const float* __restrict__ W2, const float* __restrict__ b2,
                           float* __restrict__ xadd, int rows) {
    int r = blockIdx.x * blockDim.x + threadIdx.x;
    if (r >= rows) return;
    int c = subgraphs[r * 4];
    float f0 = x[2 * c], f1 = x[2 * c + 1], f2 = aggr[r];
    float o0 = b2[0], o1 = b2[1];
    for (int j = 0; j < 128; j++) {
        float h = b1[j] + f0 * W1[j] + f1 * W1[128 + j] + f2 * W1[256 + j];
        h = h > 0.f ? h : 0.01f * h;
        o0 += h * W2[j * 2 + 0];
        o1 += h * W2[j * 2 + 1];
    }
    atomicAdd(&xadd[2 * c + 0], o0);
    atomicAdd(&xadd[2 * c + 1], o1);
}

// segment sum/count per graph
__global__ void pool_kernel(const float* __restrict__ x, const float* __restrict__ xadd,
                            const int* __restrict__ batch,
                            float* __restrict__ gsum, float* __restrict__ gcnt, int rows) {
    int r = blockIdx.x * blockDim.x + threadIdx.x;
    if (r >= rows) return;
    int b = batch[r];
    atomicAdd(&gsum[2 * b + 0], x[2 * r + 0] + xadd[2 * r + 0]);
    atomicAdd(&gsum[2 * b + 1], x[2 * r + 1] + xadd[2 * r + 1]);
    atomicAdd(&gcnt[b], 1.f);
}

// g = gsum/gcnt; out = mlp(g, 2->2->2)
__global__ void head_kernel(const float* __restrict__ gsum, const float* __restrict__ gcnt,
                            const float* __restrict__ Wh1, const float* __restrict__ bh1,
                            const float* __restrict__ Wh2, const float* __restrict__ bh2,
                            float* __restrict__ out, int ngraphs) {
    int g = threadIdx.x;
    if (g >= ngraphs) return;
    float c = gcnt[g];
    float g0 = gsum[2 * g + 0] / c;
    float g1 = gsum[2 * g + 1] / c;
    float h0 = g0 * Wh1[0] + g1 * Wh1[2] + bh1[0];
    float h1 = g0 * Wh1[1] + g1 * Wh1[3] + bh1[1];
    h0 = h0 > 0.f ? h0 : 0.01f * h0;
    h1 = h1 > 0.f ? h1 : 0.01f * h1;
    out[2 * g + 0] = h0 * Wh2[0] + h1 * Wh2[2] + bh2[0];
    out[2 * g + 1] = h0 * Wh2[1] + h1 * Wh2[3] + bh2[1];
}

extern "C" void kernel_launch(void* const* d_in, const int* in_sizes, int n_in,
                              void* d_out, int out_size, void* d_ws, size_t ws_size,
                              hipStream_t stream) {
    const float* node_feat = (const float*)d_in[0];   // (N, 8)
    const float* edge_attr = (const float*)d_in[1];   // (3N, 4)
    const float* Wn1 = (const float*)d_in[2];
    const float* bn1 = (const float*)d_in[3];
    const float* Wn2 = (const float*)d_in[4];
    const float* bn2 = (const float*)d_in[5];
    const float* We1 = (const float*)d_in[6];
    const float* be1 = (const float*)d_in[7];
    const float* We2 = (const float*)d_in[8];
    const float* be2 = (const float*)d_in[9];
    const float* strong = (const float*)d_in[10];     // (2,1,3,3)
    const float* inits  = (const float*)d_in[11];     // (1,4)
    const float* update = (const float*)d_in[12];     // (1,3,3)
    const float* Wu1 = (const float*)d_in[13];
    const float* bu1 = (const float*)d_in[14];
    const float* Wu2 = (const float*)d_in[15];
    const float* bu2 = (const float*)d_in[16];
    const float* Wh1 = (const float*)d_in[17];
    const float* bh1 = (const float*)d_in[18];
    const float* Wh2 = (const float*)d_in[19];
    const float* bh2 = (const float*)d_in[20];
    const int* subgraphs = (const int*)d_in[21];      // (N, 4)
    const int* edge_ids  = (const int*)d_in[22];      // (N, 3)
    const int* batch     = (const int*)d_in[23];      // (N,)

    const int N  = in_sizes[0] / 8;      // 4096 nodes
    const int NE = in_sizes[1] / 4;      // 12288 edges
    const int NG = out_size / 2;         // 16 graphs

    // workspace layout (floats)
    float* ws   = (float*)d_ws;
    float* x    = ws;                    // N*2
    float* e    = x + (size_t)N * 2;     // NE*2
    float* aggr = e + (size_t)NE * 2;    // N
    float* xadd = aggr + N;              // N*2
    float* gsum = xadd + (size_t)N * 2;  // NG*2
    float* gcnt = gsum + (size_t)NG * 2; // NG

    // zero the accumulator region (xadd, gsum, gcnt) — ws is poisoned before each call
    hipMemsetAsync(xadd, 0, (size_t)(N * 2 + NG * 3) * sizeof(float), stream);

    mlp_tanh_kernel<8><<<(N + 255) / 256, 256, 0, stream>>>(node_feat, Wn1, bn1, Wn2, bn2, x, N);
    mlp_tanh_kernel<4><<<(NE + 255) / 256, 256, 0, stream>>>(edge_attr, We1, be1, We2, be2, e, NE);

    pqc_kernel<<<N, 64, 0, stream>>>(x, e, subgraphs, edge_ids, strong, inits, update, aggr);

    upd_kernel<<<(N + 255) / 256, 256, 0, stream>>>(x, aggr, subgraphs, Wu1, bu1, Wu2, bu2, xadd, N);
    pool_kernel<<<(N + 255) / 256, 256, 0, stream>>>(x, xadd, batch, gsum, gcnt, N);
    head_kernel<<<1, 64, 0, stream>>>(gsum, gcnt, Wh1, bh1, Wh2, bh2, (float*)d_out, NG);
}

// Round 2
// 218.542 us; speedup vs baseline: 1.3895x; 1.3895x over previous
//
#include <hip/hip_runtime.h>
#include <math.h>

#define PI_F 3.14159265358979323846f

// ---------- complex helpers ----------
struct Cx { float re, im; };
__device__ __forceinline__ Cx cmul(Cx a, Cx b) {
    return { a.re * b.re - a.im * b.im, a.re * b.im + a.im * b.re };
}
__device__ __forceinline__ Cx cadd(Cx a, Cx b) { return { a.re + b.re, a.im + b.im }; }

struct M2 { Cx m[2][2]; };

__device__ __forceinline__ M2 mmul(const M2& A, const M2& B) {
    M2 R;
    for (int i = 0; i < 2; i++)
        for (int j = 0; j < 2; j++)
            R.m[i][j] = cadd(cmul(A.m[i][0], B.m[0][j]), cmul(A.m[i][1], B.m[1][j]));
    return R;
}
__device__ __forceinline__ M2 mry(float t) {
    float c = cosf(0.5f * t), s = sinf(0.5f * t);
    M2 R; R.m[0][0] = {c, 0}; R.m[0][1] = {-s, 0}; R.m[1][0] = {s, 0}; R.m[1][1] = {c, 0};
    return R;
}
__device__ __forceinline__ M2 mrz(float t) {
    float c = cosf(0.5f * t), s = sinf(0.5f * t);
    M2 R; R.m[0][0] = {c, -s}; R.m[0][1] = {0, 0}; R.m[1][0] = {0, 0}; R.m[1][1] = {c, s};
    return R;
}
__device__ __forceinline__ M2 mrx(float t) {
    float c = cosf(0.5f * t), s = sinf(0.5f * t);
    M2 R; R.m[0][0] = {c, 0}; R.m[0][1] = {0, -s}; R.m[1][0] = {0, -s}; R.m[1][1] = {c, 0};
    return R;
}
// Rot(phi, theta, omega) = RZ(omega) @ RY(theta) @ RZ(phi)
__device__ __forceinline__ M2 mrot(float phi, float th, float om) {
    return mmul(mmul(mrz(om), mry(th)), mrz(phi));
}

// ---------- gate application on LDS statevector (9 wires, 512 amps) ----------
// wire w -> bit (8 - w): wire 0 is the most significant bit of the flat index.

__device__ __forceinline__ void apply1(float2* st, const M2& U, int wire, int lane) {
    int bit = 8 - wire;
    int low = (1 << bit) - 1;
    for (int k = lane; k < 256; k += 64) {
        int i0 = ((k & ~low) << 1) | (k & low);
        int i1 = i0 | (1 << bit);
        float2 a = st[i0], b = st[i1];
        float2 na, nb;
        na.x = U.m[0][0].re * a.x - U.m[0][0].im * a.y + U.m[0][1].re * b.x - U.m[0][1].im * b.y;
        na.y = U.m[0][0].re * a.y + U.m[0][0].im * a.x + U.m[0][1].re * b.y + U.m[0][1].im * b.x;
        nb.x = U.m[1][0].re * a.x - U.m[1][0].im * a.y + U.m[1][1].re * b.x - U.m[1][1].im * b.y;
        nb.y = U.m[1][0].re * a.y + U.m[1][0].im * a.x + U.m[1][1].re * b.y + U.m[1][1].im * b.x;
        st[i0] = na; st[i1] = nb;
    }
    __syncthreads();
}

// index with control bit set, target bit clear; k enumerates the other 7 bits
__device__ __forceinline__ int idx_c1t0(int k, int cbit, int tbit) {
    int lo = cbit < tbit ? cbit : tbit;
    int hi = cbit < tbit ? tbit : cbit;
    int mlo = (1 << lo) - 1, mhi = (1 << hi) - 1;
    int i = ((k & ~mlo) << 1) | (k & mlo);   // insert 0 at lo
    i = ((i & ~mhi) << 1) | (i & mhi);       // insert 0 at hi
    return i | (1 << cbit);
}

// controlled-U: control wire cw, target wire tw
__device__ __forceinline__ void applyc(float2* st, const M2& U, int cw, int tw, int lane) {
    int cbit = 8 - cw, tbit = 8 - tw;
    for (int k = lane; k < 128; k += 64) {
        int i0 = idx_c1t0(k, cbit, tbit);
        int i1 = i0 | (1 << tbit);
        float2 a = st[i0], b = st[i1];
        float2 na, nb;
        na.x = U.m[0][0].re * a.x - U.m[0][0].im * a.y + U.m[0][1].re * b.x - U.m[0][1].im * b.y;
        na.y = U.m[0][0].re * a.y + U.m[0][0].im * a.x + U.m[0][1].re * b.y + U.m[0][1].im * b.x;
        nb.x = U.m[1][0].re * a.x - U.m[1][0].im * a.y + U.m[1][1].re * b.x - U.m[1][1].im * b.y;
        nb.y = U.m[1][0].re * a.y + U.m[1][0].im * a.x + U.m[1][1].re * b.y + U.m[1][1].im * b.x;
        st[i0] = na; st[i1] = nb;
    }
    __syncthreads();
}

__device__ __forceinline__ void cnot(float2* st, int cw, int tw, int lane) {
    int cbit = 8 - cw, tbit = 8 - tw;
    for (int k = lane; k < 128; k += 64) {
        int i0 = idx_c1t0(k, cbit, tbit);
        int i1 = i0 | (1 << tbit);
        float2 a = st[i0];
        st[i0] = st[i1];
        st[i1] = a;
    }
    __syncthreads();
}

// StronglyEntanglingLayers, L=1, 3 wires: Rot on each wire then CNOT ring (r=1)
__device__ __forceinline__ void sel3(float2* st, const float* w, int w0, int w1, int w2, int lane) {
    int wires[3] = { w0, w1, w2 };
    for (int j = 0; j < 3; j++) {
        M2 U = mrot(w[j * 3 + 0], w[j * 3 + 1], w[j * 3 + 2]);
        apply1(st, U, wires[j], lane);
    }
    for (int j = 0; j < 3; j++) cnot(st, wires[j], wires[(j + 1) % 3], lane);
}

// ---------- kernels ----------

// tanh(mlp(feat)) * pi, IN_DIM -> 128 -> 2, one thread per row
template <int IN_DIM>
__global__ void mlp_tanh_kernel(const float* __restrict__ feat, const float* __restrict__ W1,
                                const float* __restrict__ b1, const float* __restrict__ W2,
                                const float* __restrict__ b2, float* __restrict__ out, int rows) {
    int r = blockIdx.x * blockDim.x + threadIdx.x;
    if (r >= rows) return;
    float f[IN_DIM];
#pragma unroll
    for (int k = 0; k < IN_DIM; k++) f[k] = feat[r * IN_DIM + k];
    float o0 = b2[0], o1 = b2[1];
    for (int j = 0; j < 128; j++) {
        float h = b1[j];
#pragma unroll
        for (int k = 0; k < IN_DIM; k++) h += f[k] * W1[k * 128 + j];
        h = h > 0.f ? h : 0.01f * h;   // leaky_relu, slope 0.01
        o0 += h * W2[j * 2 + 0];
        o1 += h * W2[j * 2 + 1];
    }
    out[r * 2 + 0] = tanhf(o0) * PI_F;
    out[r * 2 + 1] = tanhf(o1) * PI_F;
}

// one 64-thread block per sample; full 512-amp statevector in LDS
__global__ __launch_bounds__(64) void pqc_kernel(
        const float* __restrict__ x, const float* __restrict__ e,
        const int* __restrict__ subgraphs, const int* __restrict__ edge_ids,
        const float* __restrict__ strong, const float* __restrict__ inits,
        const float* __restrict__ update, float* __restrict__ aggr) {
    __shared__ float2 st[512];
    int s = blockIdx.x;
    int lane = threadIdx.x;

    for (int k = lane; k < 512; k += 64) st[k] = make_float2(0.f, 0.f);
    __syncthreads();
    if (lane == 0) st[0] = make_float2(1.f, 0.f);
    __syncthreads();

    // q_in: rows 0..2 = e[edge_ids[s]], rows 3..6 = x[subgraphs[s]]
    float ang[7][2];
    for (int j = 0; j < 3; j++) {
        int eid = edge_ids[s * 3 + j];
        ang[j][0] = e[2 * eid]; ang[j][1] = e[2 * eid + 1];
    }
    for (int j = 0; j < 4; j++) {
        int nid = subgraphs[s * 4 + j];
        ang[3 + j][0] = x[2 * nid]; ang[3 + j][1] = x[2 * nid + 1];
    }

    // encoding layer
    for (int i = 0; i < 3; i++) {
        apply1(st, mry(ang[i][0]), i, lane);
        apply1(st, mrz(ang[i][1]), i, lane);
    }
    for (int i = 0; i < 4; i++) {
        apply1(st, mry(ang[3 + i][0]), 3 + i, lane);
        apply1(st, mrz(ang[3 + i][1]), 3 + i, lane);
    }

    float v0 = inits[0], v1 = inits[1], v2 = inits[2], v3 = inits[3];
    M2 crx = mrx(v0), cry1 = mry(v1), crz = mrz(v2), cry2 = mry(v3);
    for (int i = 0; i < 3; i++) {
        int ew = i, nb = 4 + i, a1 = 7, a2 = 8;
        applyc(st, crx, nb, a1, lane);
        applyc(st, cry1, ew, a1, lane);
        applyc(st, crz, nb, a2, lane);
        applyc(st, cry2, ew, a2, lane);
        sel3(st, strong, ew, nb, a1, lane);       // strong[0]
        sel3(st, strong + 9, a1, nb, a2, lane);   // strong[1]
    }
    sel3(st, update, 3, 7, 8, lane);

    // <X_3>: wire 3 -> bit 5 (value 32); 2*Re(conj(z0)*z1) over the 8x32 other dims
    float acc = 0.f;
    for (int k = lane; k < 256; k += 64) {
        int a = k >> 5, b = k & 31;
        int j0 = (a << 6) | b;
        int j1 = j0 | 32;
        float2 z0 = st[j0], z1 = st[j1];
        acc += z0.x * z1.x + z0.y * z1.y;
    }
    acc *= 2.f;
    for (int off = 32; off > 0; off >>= 1) acc += __shfl_down(acc, off);
    if (lane == 0) aggr[s] = acc;
}

// upd = mlp([x[center], aggr], 3->128->2); scatter-add into xadd at center
__global__ void upd_kernel(const float* __restrict__ x, const float* __restrict__ aggr,
                           const int* __restrict__ subgraphs,
                           const float* __restrict__ W1, const float* __restrict__ b1,
                           const float* __restrict__ W2, const float* __restrict__ b2,
                           float* __restrict__ xadd, int rows) {
    int r = blockIdx.x * blockDim.x + threadIdx.x;
    if (r >= rows) return;
    int c = subgraphs[r * 4];
    float f0 = x[2 * c], f1 = x[2 * c + 1], f2 = aggr[r];
    float o0 = b2[0], o1 = b2[1];
    for (int j = 0; j < 128; j++) {
        float h = b1[j] + f0 * W1[j] + f1 * W1[128 + j] + f2 * W1[256 + j];
        h = h > 0.f ? h : 0.01f * h;
        o0 += h * W2[j * 2 + 0];
        o1 += h * W2[j * 2 + 1];
    }
    atomicAdd(&xadd[2 * c + 0], o0);
    atomicAdd(&xadd[2 * c + 1], o1);
}

// segment sum/count per graph — hierarchical: wave shuffle -> LDS bins -> one
// global atomic per bin per block. Replaces 12288 contended global atomics
// (~84 us) with ~768 spread over 48 addresses.
#define MAX_GRAPHS 64
__global__ __launch_bounds__(256) void pool_kernel(
        const float* __restrict__ x, const float* __restrict__ xadd,
        const int* __restrict__ batch,
        float* __restrict__ gsum, float* __restrict__ gcnt, int rows, int ngraphs) {
    __shared__ float bins[3 * MAX_GRAPHS];
    for (int i = threadIdx.x; i < 3 * ngraphs; i += blockDim.x) bins[i] = 0.f;
    __syncthreads();

    int r = blockIdx.x * blockDim.x + threadIdx.x;
    int lane = threadIdx.x & 63;
    bool active = r < rows;
    int b = 0; float v0 = 0.f, v1 = 0.f, cc = 0.f;
    if (active) {
        b = batch[r];
        v0 = x[2 * r + 0] + xadd[2 * r + 0];
        v1 = x[2 * r + 1] + xadd[2 * r + 1];
        cc = 1.f;
    }
    // fast path: whole wave same graph (common: contiguous batch) and fully active
    int b0 = __shfl(b, 0);
    bool uni = __all(active && b == b0);
    if (uni) {
        for (int off = 32; off > 0; off >>= 1) {
            v0 += __shfl_down(v0, off);
            v1 += __shfl_down(v1, off);
        }
        if (lane == 0) {
            atomicAdd(&bins[3 * b0 + 0], v0);
            atomicAdd(&bins[3 * b0 + 1], v1);
            atomicAdd(&bins[3 * b0 + 2], 64.f);
        }
    } else if (active) {
        atomicAdd(&bins[3 * b + 0], v0);
        atomicAdd(&bins[3 * b + 1], v1);
        atomicAdd(&bins[3 * b + 2], cc);
    }
    __syncthreads();

    for (int i = threadIdx.x; i < ngraphs; i += blockDim.x) {
        float s0 = bins[3 * i + 0], s1 = bins[3 * i + 1], sc = bins[3 * i + 2];
        if (s0 != 0.f || s1 != 0.f || sc != 0.f) {
            atomicAdd(&gsum[2 * i + 0], s0);
            atomicAdd(&gsum[2 * i + 1], s1);
            atomicAdd(&gcnt[i], sc);
        }
    }
}

// g = gsum/gcnt; out = mlp(g, 2->2->2)
__global__ void head_kernel(const float* __restrict__ gsum, const float* __restrict__ gcnt,
                            const float* __restrict__ Wh1, const float* __restrict__ bh1,
                            const float* __restrict__ Wh2, const float* __restrict__ bh2,
                            float* __restrict__ out, int ngraphs) {
    int g = threadIdx.x;
    if (g >= ngraphs) return;
    float c = gcnt[g];
    float g0 = gsum[2 * g + 0] / c;
    float g1 = gsum[2 * g + 1] / c;
    float h0 = g0 * Wh1[0] + g1 * Wh1[2] + bh1[0];
    float h1 = g0 * Wh1[1] + g1 * Wh1[3] + bh1[1];
    h0 = h0 > 0.f ? h0 : 0.01f * h0;
    h1 = h1 > 0.f ? h1 : 0.01f * h1;
    out[2 * g + 0] = h0 * Wh2[0] + h1 * Wh2[2] + bh2[0];
    out[2 * g + 1] = h0 * Wh2[1] + h1 * Wh2[3] + bh2[1];
}

extern "C" void kernel_launch(void* const* d_in, const int* in_sizes, int n_in,
                              void* d_out, int out_size, void* d_ws, size_t ws_size,
                              hipStream_t stream) {
    const float* node_feat = (const float*)d_in[0];   // (N, 8)
    const float* edge_attr = (const float*)d_in[1];   // (3N, 4)
    const float* Wn1 = (const float*)d_in[2];
    const float* bn1 = (const float*)d_in[3];
    const float* Wn2 = (const float*)d_in[4];
    const float* bn2 = (const float*)d_in[5];
    const float* We1 = (const float*)d_in[6];
    const float* be1 = (const float*)d_in[7];
    const float* We2 = (const float*)d_in[8];
    const float* be2 = (const float*)d_in[9];
    const float* strong = (const float*)d_in[10];     // (2,1,3,3)
    const float* inits  = (const float*)d_in[11];     // (1,4)
    const float* update = (const float*)d_in[12];     // (1,3,3)
    const float* Wu1 = (const float*)d_in[13];
    const float* bu1 = (const float*)d_in[14];
    const float* Wu2 = (const float*)d_in[15];
    const float* bu2 = (const float*)d_in[16];
    const float* Wh1 = (const float*)d_in[17];
    const float* bh1 = (const float*)d_in[18];
    const float* Wh2 = (const float*)d_in[19];
    const float* bh2 = (const float*)d_in[20];
    const int* subgraphs = (const int*)d_in[21];      // (N, 4)
    const int* edge_ids  = (const int*)d_in[22];      // (N, 3)
    const int* batch     = (const int*)d_in[23];      // (N,)

    const int N  = in_sizes[0] / 8;      // 4096 nodes
    const int NE = in_sizes[1] / 4;      // 12288 edges
    const int NG = out_size / 2;         // 16 graphs

    // workspace layout (floats)
    float* ws   = (float*)d_ws;
    float* x    = ws;                    // N*2
    float* e    = x + (size_t)N * 2;     // NE*2
    float* aggr = e + (size_t)NE * 2;    // N
    float* xadd = aggr + N;              // N*2
    float* gsum = xadd + (size_t)N * 2;  // NG*2
    float* gcnt = gsum + (size_t)NG * 2; // NG

    // zero the accumulator region (xadd, gsum, gcnt) — ws is poisoned before each call
    hipMemsetAsync(xadd, 0, (size_t)(N * 2 + NG * 3) * sizeof(float), stream);

    mlp_tanh_kernel<8><<<(N + 255) / 256, 256, 0, stream>>>(node_feat, Wn1, bn1, Wn2, bn2, x, N);
    mlp_tanh_kernel<4><<<(NE + 255) / 256, 256, 0, stream>>>(edge_attr, We1, be1, We2, be2, e, NE);

    pqc_kernel<<<N, 64, 0, stream>>>(x, e, subgraphs, edge_ids, strong, inits, update, aggr);

    upd_kernel<<<(N + 255) / 256, 256, 0, stream>>>(x, aggr, subgraphs, Wu1, bu1, Wu2, bu2, xadd, N);
    pool_kernel<<<(N + 255) / 256, 256, 0, stream>>>(x, xadd, batch, gsum, gcnt, N, NG);
    head_kernel<<<1, 64, 0, stream>>>(gsum, gcnt, Wh1, bh1, Wh2, bh2, (float*)d_out, NG);
}

// Round 3
// 216.429 us; speedup vs baseline: 1.4031x; 1.0098x over previous
//
#include <hip/hip_runtime.h>
#include <math.h>

#define PI_F 3.14159265358979323846f

// ---------- complex helpers (float2 as complex) ----------
__device__ __forceinline__ float2 cmul2(float2 a, float2 b) {
    return make_float2(a.x * b.x - a.y * b.y, a.x * b.y + a.y * b.x);
}
// u*a + v*b
__device__ __forceinline__ float2 cmac2(float2 u, float2 a, float2 v, float2 b) {
    float2 r;
    r.x = u.x * a.x - u.y * a.y + v.x * b.x - v.y * b.y;
    r.y = u.x * a.y + u.y * a.x + v.x * b.y + v.y * b.x;
    return r;
}

struct M4 { float2 u00, u01, u10, u11; };

__device__ __forceinline__ M4 mmul4(const M4& A, const M4& B) {
    M4 R;
    R.u00 = cmac2(A.u00, B.u00, A.u01, B.u10);
    R.u01 = cmac2(A.u00, B.u01, A.u01, B.u11);
    R.u10 = cmac2(A.u10, B.u00, A.u11, B.u10);
    R.u11 = cmac2(A.u10, B.u01, A.u11, B.u11);
    return R;
}
__device__ __forceinline__ M4 mry(float t) {
    float c = cosf(0.5f * t), s = sinf(0.5f * t);
    M4 R; R.u00 = {c, 0}; R.u01 = {-s, 0}; R.u10 = {s, 0}; R.u11 = {c, 0};
    return R;
}
__device__ __forceinline__ M4 mrz(float t) {
    float c = cosf(0.5f * t), s = sinf(0.5f * t);
    M4 R; R.u00 = {c, -s}; R.u01 = {0, 0}; R.u10 = {0, 0}; R.u11 = {c, s};
    return R;
}
__device__ __forceinline__ M4 mrx(float t) {
    float c = cosf(0.5f * t), s = sinf(0.5f * t);
    M4 R; R.u00 = {c, 0}; R.u01 = {0, -s}; R.u10 = {0, -s}; R.u11 = {c, 0};
    return R;
}
// Rot(phi, theta, omega) = RZ(omega) @ RY(theta) @ RZ(phi)
__device__ __forceinline__ M4 mrot(float phi, float th, float om) {
    return mmul4(mmul4(mrz(om), mry(th)), mrz(phi));
}

__device__ __forceinline__ float2 shflx(float2 v, int mask) {
    return make_float2(__shfl_xor(v.x, mask, 64), __shfl_xor(v.y, mask, 64));
}

// ---------- register statevector: idx = lane*8 + r ----------
// idx bit b: b in [0,2] -> register bit b; b in [3,8] -> lane bit (b-3).
// wire w -> idx bit (8-w). Wires 0..5 = lane bits 5..0; wires 6,7,8 = reg bits 2,1,0.

// single-qubit gate on register bit TB
template <int TB>
__device__ __forceinline__ void rot_reg(const M4& U, float2 (&amp)[8]) {
#pragma unroll
    for (int r = 0; r < 8; r++)
        if (((r >> TB) & 1) == 0) {
            int r1 = r | (1 << TB);
            float2 a = amp[r], b = amp[r1];
            amp[r]  = cmac2(U.u00, a, U.u01, b);
            amp[r1] = cmac2(U.u10, a, U.u11, b);
        }
}

// single-qubit gate on lane bit LB
template <int LB>
__device__ __forceinline__ void rot_lane(const M4& U, float2 (&amp)[8], int lane) {
    bool hi = (lane >> LB) & 1;
    float2 cA = hi ? U.u11 : U.u00;
    float2 cB = hi ? U.u10 : U.u01;
#pragma unroll
    for (int r = 0; r < 8; r++) {
        float2 o = shflx(amp[r], 1 << LB);
        amp[r] = cmac2(cA, amp[r], cB, o);
    }
}

template <int WIRE>
__device__ __forceinline__ void rot1(const M4& U, float2 (&amp)[8], int lane) {
    constexpr int BIT = 8 - WIRE;
    if constexpr (BIT < 3) rot_reg<BIT>(U, amp);
    else rot_lane<BIT - 3>(U, amp, lane);
}

// controlled rotation; all uses have a register-bit target (wires 7/8)
template <int CW, int TW>
__device__ __forceinline__ void crot(const M4& U, float2 (&amp)[8], int lane) {
    constexpr int CBIT = 8 - CW, TBIT = 8 - TW;
    static_assert(TBIT < 3, "controlled targets are reg bits here");
    if constexpr (CBIT >= 3) {
        bool c = (lane >> (CBIT - 3)) & 1;
        M4 E;
        E.u00 = c ? U.u00 : make_float2(1.f, 0.f);
        E.u01 = c ? U.u01 : make_float2(0.f, 0.f);
        E.u10 = c ? U.u10 : make_float2(0.f, 0.f);
        E.u11 = c ? U.u11 : make_float2(1.f, 0.f);
        rot_reg<TBIT>(E, amp);
    } else {
#pragma unroll
        for (int r = 0; r < 8; r++)
            if (((r >> CBIT) & 1) == 1 && ((r >> TBIT) & 1) == 0) {
                int r1 = r | (1 << TBIT);
                float2 a = amp[r], b = amp[r1];
                amp[r]  = cmac2(U.u00, a, U.u01, b);
                amp[r1] = cmac2(U.u10, a, U.u11, b);
            }
    }
}

template <int CW, int TW>
__device__ __forceinline__ void cnotg(float2 (&amp)[8], int lane) {
    constexpr int CBIT = 8 - CW, TBIT = 8 - TW;
    if constexpr (CBIT < 3 && TBIT < 3) {
        // reg control, reg target: conditional register swap
#pragma unroll
        for (int r = 0; r < 8; r++)
            if (((r >> CBIT) & 1) == 1 && ((r >> TBIT) & 1) == 0) {
                int r1 = r | (1 << TBIT);
                float2 t = amp[r]; amp[r] = amp[r1]; amp[r1] = t;
            }
    } else if constexpr (CBIT >= 3 && TBIT < 3) {
        // lane control, reg target: per-lane select
        bool c = (lane >> (CBIT - 3)) & 1;
#pragma unroll
        for (int r = 0; r < 8; r++)
            if (((r >> TBIT) & 1) == 0) {
                int r1 = r | (1 << TBIT);
                float2 t0 = amp[r], t1 = amp[r1];
                amp[r]  = c ? t1 : t0;
                amp[r1] = c ? t0 : t1;
            }
    } else if constexpr (CBIT < 3 && TBIT >= 3) {
        // reg control, lane target: shuffle only the controlled regs (uniform flow)
#pragma unroll
        for (int r = 0; r < 8; r++)
            if (((r >> CBIT) & 1) == 1) {
                amp[r] = shflx(amp[r], 1 << (TBIT - 3));
            }
    } else {
        // lane control, lane target
        bool c = (lane >> (CBIT - 3)) & 1;
#pragma unroll
        for (int r = 0; r < 8; r++) {
            float2 o = shflx(amp[r], 1 << (TBIT - 3));
            amp[r] = c ? o : amp[r];
        }
    }
}

// StronglyEntanglingLayers, L=1, 3 wires (compile-time wires)
template <int W0, int W1, int W2>
__device__ __forceinline__ void sel3(const float* __restrict__ w, float2 (&amp)[8], int lane) {
    rot1<W0>(mrot(w[0], w[1], w[2]), amp, lane);
    rot1<W1>(mrot(w[3], w[4], w[5]), amp, lane);
    rot1<W2>(mrot(w[6], w[7], w[8]), amp, lane);
    cnotg<W0, W1>(amp, lane);
    cnotg<W1, W2>(amp, lane);
    cnotg<W2, W0>(amp, lane);
}

template <int I>
__device__ __forceinline__ void block_i(float2 (&amp)[8], const M4& crx, const M4& cry1,
                                        const M4& crz, const M4& cry2,
                                        const float* __restrict__ strong, int lane) {
    constexpr int EW = I, NB = 4 + I;
    crot<NB, 7>(crx,  amp, lane);
    crot<EW, 7>(cry1, amp, lane);
    crot<NB, 8>(crz,  amp, lane);
    crot<EW, 8>(cry2, amp, lane);
    sel3<EW, NB, 7>(strong,     amp, lane);
    sel3<7, NB, 8>(strong + 9,  amp, lane);
}

// ---------- kernels ----------

// tanh(mlp(feat)) * pi, IN_DIM -> 128 -> 2, one thread per row
template <int IN_DIM>
__global__ void mlp_tanh_kernel(const float* __restrict__ feat, const float* __restrict__ W1,
                                const float* __restrict__ b1, const float* __restrict__ W2,
                                const float* __restrict__ b2, float* __restrict__ out, int rows) {
    int r = blockIdx.x * blockDim.x + threadIdx.x;
    if (r >= rows) return;
    float f[IN_DIM];
#pragma unroll
    for (int k = 0; k < IN_DIM; k++) f[k] = feat[r * IN_DIM + k];
    float o0 = b2[0], o1 = b2[1];
    for (int j = 0; j < 128; j++) {
        float h = b1[j];
#pragma unroll
        for (int k = 0; k < IN_DIM; k++) h += f[k] * W1[k * 128 + j];
        h = h > 0.f ? h : 0.01f * h;   // leaky_relu, slope 0.01
        o0 += h * W2[j * 2 + 0];
        o1 += h * W2[j * 2 + 1];
    }
    out[r * 2 + 0] = tanhf(o0) * PI_F;
    out[r * 2 + 1] = tanhf(o1) * PI_F;
}

// 4 samples per 256-thread block, one wave per sample; statevector in registers.
__global__ __launch_bounds__(256) void pqc_kernel(
        const float* __restrict__ x, const float* __restrict__ e,
        const int* __restrict__ subgraphs, const int* __restrict__ edge_ids,
        const float* __restrict__ strong, const float* __restrict__ inits,
        const float* __restrict__ update, float* __restrict__ aggr, int ntot) {
    int wave = threadIdx.x >> 6;
    int lane = threadIdx.x & 63;
    int s = blockIdx.x * 4 + wave;
    if (s >= ntot) return;   // wave-uniform

    // angles: rows 0..2 = e[edge_ids[s]], rows 3..6 = x[subgraphs[s]]
    float ang[7][2];
    for (int j = 0; j < 3; j++) {
        int eid = edge_ids[s * 3 + j];
        ang[j][0] = e[2 * eid]; ang[j][1] = e[2 * eid + 1];
    }
    for (int j = 0; j < 4; j++) {
        int nid = subgraphs[s * 4 + j];
        ang[3 + j][0] = x[2 * nid]; ang[3 + j][1] = x[2 * nid + 1];
    }

    // Encoding layer acts on |0..0> -> product state, computed in closed form.
    // v_w = [cos(a/2) e^{-ib/2}, sin(a/2) e^{+ib/2}]
    float2 c = make_float2(1.f, 0.f);
#pragma unroll
    for (int w = 0; w < 6; w++) {
        float a = ang[w][0], b = ang[w][1];
        float ca = cosf(0.5f * a), sa = sinf(0.5f * a);
        float cb = cosf(0.5f * b), sb = sinf(0.5f * b);
        float2 v0 = make_float2(ca * cb, -ca * sb);
        float2 v1 = make_float2(sa * cb,  sa * sb);
        int bit = (lane >> (5 - w)) & 1;
        c = cmul2(c, bit ? v1 : v0);
    }
    float2 amp[8];
#pragma unroll
    for (int r = 0; r < 8; r++) amp[r] = make_float2(0.f, 0.f);
    {
        float a = ang[6][0], b = ang[6][1];
        float ca = cosf(0.5f * a), sa = sinf(0.5f * a);
        float cb = cosf(0.5f * b), sb = sinf(0.5f * b);
        amp[0] = cmul2(c, make_float2(ca * cb, -ca * sb));  // wire6=0 (reg bit 2)
        amp[4] = cmul2(c, make_float2(sa * cb,  sa * sb));  // wire6=1
    }

    M4 crx  = mrx(inits[0]);
    M4 cry1 = mry(inits[1]);
    M4 crz  = mrz(inits[2]);
    M4 cry2 = mry(inits[3]);

    block_i<0>(amp, crx, cry1, crz, cry2, strong, lane);
    block_i<1>(amp, crx, cry1, crz, cry2, strong, lane);
    block_i<2>(amp, crx, cry1, crz, cry2, strong, lane);
    sel3<3, 7, 8>(update, amp, lane);

    // <X_3>: wire 3 -> idx bit 5 -> lane bit 2. Each pair counted from both
    // sides => full-lane sum already equals 2 * sum_over_pairs.
    float acc = 0.f;
#pragma unroll
    for (int r = 0; r < 8; r++) {
        float2 o = shflx(amp[r], 4);
        acc += amp[r].x * o.x + amp[r].y * o.y;
    }
    for (int off = 32; off > 0; off >>= 1) acc += __shfl_down(acc, off, 64);
    if (lane == 0) aggr[s] = acc;
}

// upd = mlp([x[center], aggr], 3->128->2); scatter-add into xadd at center
__global__ void upd_kernel(const float* __restrict__ x, const float* __restrict__ aggr,
                           const int* __restrict__ subgraphs,
                           const float* __restrict__ W1, const float* __restrict__ b1,
                           const float* __restrict__ W2, const float* __restrict__ b2,
                           float* __restrict__ xadd, int rows) {
    int r = blockIdx.x * blockDim.x + threadIdx.x;
    if (r >= rows) return;
    int c = subgraphs[r * 4];
    float f0 = x[2 * c], f1 = x[2 * c + 1], f2 = aggr[r];
    float o0 = b2[0], o1 = b2[1];
    for (int j = 0; j < 128; j++) {
        float h = b1[j] + f0 * W1[j] + f1 * W1[128 + j] + f2 * W1[256 + j];
        h = h > 0.f ? h : 0.01f * h;
        o0 += h * W2[j * 2 + 0];
        o1 += h * W2[j * 2 + 1];
    }
    atomicAdd(&xadd[2 * c + 0], o0);
    atomicAdd(&xadd[2 * c + 1], o1);
}

// segment sum/count per graph — hierarchical: wave shuffle -> LDS bins -> one
// global atomic per bin per block.
#define MAX_GRAPHS 64
__global__ __launch_bounds__(256) void pool_kernel(
        const float* __restrict__ x, const float* __restrict__ xadd,
        const int* __restrict__ batch,
        float* __restrict__ gsum, float* __restrict__ gcnt, int rows, int ngraphs) {
    __shared__ float bins[3 * MAX_GRAPHS];
    for (int i = threadIdx.x; i < 3 * ngraphs; i += blockDim.x) bins[i] = 0.f;
    __syncthreads();

    int r = blockIdx.x * blockDim.x + threadIdx.x;
    int lane = threadIdx.x & 63;
    bool active = r < rows;
    int b = 0; float v0 = 0.f, v1 = 0.f, cc = 0.f;
    if (active) {
        b = batch[r];
        v0 = x[2 * r + 0] + xadd[2 * r + 0];
        v1 = x[2 * r + 1] + xadd[2 * r + 1];
        cc = 1.f;
    }
    int b0 = __shfl(b, 0);
    bool uni = __all(active && b == b0);
    if (uni) {
        for (int off = 32; off > 0; off >>= 1) {
            v0 += __shfl_down(v0, off);
            v1 += __shfl_down(v1, off);
        }
        if (lane == 0) {
            atomicAdd(&bins[3 * b0 + 0], v0);
            atomicAdd(&bins[3 * b0 + 1], v1);
            atomicAdd(&bins[3 * b0 + 2], 64.f);
        }
    } else if (active) {
        atomicAdd(&bins[3 * b + 0], v0);
        atomicAdd(&bins[3 * b + 1], v1);
        atomicAdd(&bins[3 * b + 2], cc);
    }
    __syncthreads();

    for (int i = threadIdx.x; i < ngraphs; i += blockDim.x) {
        float s0 = bins[3 * i + 0], s1 = bins[3 * i + 1], sc = bins[3 * i + 2];
        if (s0 != 0.f || s1 != 0.f || sc != 0.f) {
            atomicAdd(&gsum[2 * i + 0], s0);
            atomicAdd(&gsum[2 * i + 1], s1);
            atomicAdd(&gcnt[i], sc);
        }
    }
}

// g = gsum/gcnt; out = mlp(g, 2->2->2)
__global__ void head_kernel(const float* __restrict__ gsum, const float* __restrict__ gcnt,
                            const float* __restrict__ Wh1, const float* __restrict__ bh1,
                            const float* __restrict__ Wh2, const float* __restrict__ bh2,
                            float* __restrict__ out, int ngraphs) {
    int g = threadIdx.x;
    if (g >= ngraphs) return;
    float c = gcnt[g];
    float g0 = gsum[2 * g + 0] / c;
    float g1 = gsum[2 * g + 1] / c;
    float h0 = g0 * Wh1[0] + g1 * Wh1[2] + bh1[0];
    float h1 = g0 * Wh1[1] + g1 * Wh1[3] + bh1[1];
    h0 = h0 > 0.f ? h0 : 0.01f * h0;
    h1 = h1 > 0.f ? h1 : 0.01f * h1;
    out[2 * g + 0] = h0 * Wh2[0] + h1 * Wh2[2] + bh2[0];
    out[2 * g + 1] = h0 * Wh2[1] + h1 * Wh2[3] + bh2[1];
}

extern "C" void kernel_launch(void* const* d_in, const int* in_sizes, int n_in,
                              void* d_out, int out_size, void* d_ws, size_t ws_size,
                              hipStream_t stream) {
    const float* node_feat = (const float*)d_in[0];   // (N, 8)
    const float* edge_attr = (const float*)d_in[1];   // (3N, 4)
    const float* Wn1 = (const float*)d_in[2];
    const float* bn1 = (const float*)d_in[3];
    const float* Wn2 = (const float*)d_in[4];
    const float* bn2 = (const float*)d_in[5];
    const float* We1 = (const float*)d_in[6];
    const float* be1 = (const float*)d_in[7];
    const float* We2 = (const float*)d_in[8];
    const float* be2 = (const float*)d_in[9];
    const float* strong = (const float*)d_in[10];     // (2,1,3,3)
    const float* inits  = (const float*)d_in[11];     // (1,4)
    const float* update = (const float*)d_in[12];     // (1,3,3)
    const float* Wu1 = (const float*)d_in[13];
    const float* bu1 = (const float*)d_in[14];
    const float* Wu2 = (const float*)d_in[15];
    const float* bu2 = (const float*)d_in[16];
    const float* Wh1 = (const float*)d_in[17];
    const float* bh1 = (const float*)d_in[18];
    const float* Wh2 = (const float*)d_in[19];
    const float* bh2 = (const float*)d_in[20];
    const int* subgraphs = (const int*)d_in[21];      // (N, 4)
    const int* edge_ids  = (const int*)d_in[22];      // (N, 3)
    const int* batch     = (const int*)d_in[23];      // (N,)

    const int N  = in_sizes[0] / 8;      // 4096 nodes
    const int NE = in_sizes[1] / 4;      // 12288 edges
    const int NG = out_size / 2;         // 16 graphs

    // workspace layout (floats)
    float* ws   = (float*)d_ws;
    float* x    = ws;                    // N*2
    float* e    = x + (size_t)N * 2;     // NE*2
    float* aggr = e + (size_t)NE * 2;    // N
    float* xadd = aggr + N;              // N*2
    float* gsum = xadd + (size_t)N * 2;  // NG*2
    float* gcnt = gsum + (size_t)NG * 2; // NG

    // zero the accumulator region (xadd, gsum, gcnt)
    hipMemsetAsync(xadd, 0, (size_t)(N * 2 + NG * 3) * sizeof(float), stream);

    mlp_tanh_kernel<8><<<(N + 255) / 256, 256, 0, stream>>>(node_feat, Wn1, bn1, Wn2, bn2, x, N);
    mlp_tanh_kernel<4><<<(NE + 255) / 256, 256, 0, stream>>>(edge_attr, We1, be1, We2, be2, e, NE);

    pqc_kernel<<<(N + 3) / 4, 256, 0, stream>>>(x, e, subgraphs, edge_ids, strong, inits, update, aggr, N);

    upd_kernel<<<(N + 255) / 256, 256, 0, stream>>>(x, aggr, subgraphs, Wu1, bu1, Wu2, bu2, xadd, N);
    pool_kernel<<<(N + 255) / 256, 256, 0, stream>>>(x, xadd, batch, gsum, gcnt, N, NG);
    head_kernel<<<1, 64, 0, stream>>>(gsum, gcnt, Wh1, bh1, Wh2, bh2, (float*)d_out, NG);
}

// Round 4
// 162.686 us; speedup vs baseline: 1.8666x; 1.3303x over previous
//
#include <hip/hip_runtime.h>
#include <math.h>

#define PI_F 3.14159265358979323846f

// ---------- complex helpers (float2 as complex) ----------
__device__ __forceinline__ float2 cmul2(float2 a, float2 b) {
    return make_float2(a.x * b.x - a.y * b.y, a.x * b.y + a.y * b.x);
}
// u*a + v*b
__device__ __forceinline__ float2 cmac2(float2 u, float2 a, float2 v, float2 b) {
    float2 r;
    r.x = u.x * a.x - u.y * a.y + v.x * b.x - v.y * b.y;
    r.y = u.x * a.y + u.y * a.x + v.x * b.y + v.y * b.x;
    return r;
}

struct M4 { float2 u00, u01, u10, u11; };

__device__ __forceinline__ M4 mmul4(const M4& A, const M4& B) {
    M4 R;
    R.u00 = cmac2(A.u00, B.u00, A.u01, B.u10);
    R.u01 = cmac2(A.u00, B.u01, A.u01, B.u11);
    R.u10 = cmac2(A.u10, B.u00, A.u11, B.u10);
    R.u11 = cmac2(A.u10, B.u01, A.u11, B.u11);
    return R;
}
__device__ __forceinline__ M4 mry(float t) {
    float c = cosf(0.5f * t), s = sinf(0.5f * t);
    M4 R; R.u00 = {c, 0}; R.u01 = {-s, 0}; R.u10 = {s, 0}; R.u11 = {c, 0};
    return R;
}
__device__ __forceinline__ M4 mrz(float t) {
    float c = cosf(0.5f * t), s = sinf(0.5f * t);
    M4 R; R.u00 = {c, -s}; R.u01 = {0, 0}; R.u10 = {0, 0}; R.u11 = {c, s};
    return R;
}
__device__ __forceinline__ M4 mrx(float t) {
    float c = cosf(0.5f * t), s = sinf(0.5f * t);
    M4 R; R.u00 = {c, 0}; R.u01 = {0, -s}; R.u10 = {0, -s}; R.u11 = {c, 0};
    return R;
}
// Rot(phi, theta, omega) = RZ(omega) @ RY(theta) @ RZ(phi)
__device__ __forceinline__ M4 mrot(float phi, float th, float om) {
    return mmul4(mmul4(mrz(om), mry(th)), mrz(phi));
}

__device__ __forceinline__ float2 shflx(float2 v, int mask) {
    return make_float2(__shfl_xor(v.x, mask, 64), __shfl_xor(v.y, mask, 64));
}

// load an M4 from wave-uniform global memory (compiler emits scalar loads)
__device__ __forceinline__ M4 ldm(const float* __restrict__ g) {
    M4 M;
    M.u00 = make_float2(g[0], g[1]); M.u01 = make_float2(g[2], g[3]);
    M.u10 = make_float2(g[4], g[5]); M.u11 = make_float2(g[6], g[7]);
    return M;
}

// ---------- register statevector: idx = lane*8 + r ----------
// idx bit b: b in [0,2] -> register bit b; b in [3,8] -> lane bit (b-3).
// wire w -> idx bit (8-w). Wires 0..5 = lane bits 5..0; wires 6,7,8 = reg bits 2,1,0.

// single-qubit gate on register bit TB
template <int TB>
__device__ __forceinline__ void rot_reg(const M4& U, float2 (&amp)[8]) {
#pragma unroll
    for (int r = 0; r < 8; r++)
        if (((r >> TB) & 1) == 0) {
            int r1 = r | (1 << TB);
            float2 a = amp[r], b = amp[r1];
            amp[r]  = cmac2(U.u00, a, U.u01, b);
            amp[r1] = cmac2(U.u10, a, U.u11, b);
        }
}

// single-qubit gate on lane bit LB
template <int LB>
__device__ __forceinline__ void rot_lane(const M4& U, float2 (&amp)[8], int lane) {
    bool hi = (lane >> LB) & 1;
    float2 cA = hi ? U.u11 : U.u00;
    float2 cB = hi ? U.u10 : U.u01;
#pragma unroll
    for (int r = 0; r < 8; r++) {
        float2 o = shflx(amp[r], 1 << LB);
        amp[r] = cmac2(cA, amp[r], cB, o);
    }
}

template <int WIRE>
__device__ __forceinline__ void rot1(const M4& U, float2 (&amp)[8], int lane) {
    constexpr int BIT = 8 - WIRE;
    if constexpr (BIT < 3) rot_reg<BIT>(U, amp);
    else rot_lane<BIT - 3>(U, amp, lane);
}

// controlled rotation; all uses have a register-bit target (wires 7/8)
template <int CW, int TW>
__device__ __forceinline__ void crot(const M4& U, float2 (&amp)[8], int lane) {
    constexpr int CBIT = 8 - CW, TBIT = 8 - TW;
    static_assert(TBIT < 3, "controlled targets are reg bits here");
    if constexpr (CBIT >= 3) {
        bool c = (lane >> (CBIT - 3)) & 1;
        M4 E;
        E.u00 = c ? U.u00 : make_float2(1.f, 0.f);
        E.u01 = c ? U.u01 : make_float2(0.f, 0.f);
        E.u10 = c ? U.u10 : make_float2(0.f, 0.f);
        E.u11 = c ? U.u11 : make_float2(1.f, 0.f);
        rot_reg<TBIT>(E, amp);
    } else {
#pragma unroll
        for (int r = 0; r < 8; r++)
            if (((r >> CBIT) & 1) == 1 && ((r >> TBIT) & 1) == 0) {
                int r1 = r | (1 << TBIT);
                float2 a = amp[r], b = amp[r1];
                amp[r]  = cmac2(U.u00, a, U.u01, b);
                amp[r1] = cmac2(U.u10, a, U.u11, b);
            }
    }
}

template <int CW, int TW>
__device__ __forceinline__ void cnotg(float2 (&amp)[8], int lane) {
    constexpr int CBIT = 8 - CW, TBIT = 8 - TW;
    if constexpr (CBIT < 3 && TBIT < 3) {
        // reg control, reg target: conditional register swap
#pragma unroll
        for (int r = 0; r < 8; r++)
            if (((r >> CBIT) & 1) == 1 && ((r >> TBIT) & 1) == 0) {
                int r1 = r | (1 << TBIT);
                float2 t = amp[r]; amp[r] = amp[r1]; amp[r1] = t;
            }
    } else if constexpr (CBIT >= 3 && TBIT < 3) {
        // lane control, reg target: per-lane select
        bool c = (lane >> (CBIT - 3)) & 1;
#pragma unroll
        for (int r = 0; r < 8; r++)
            if (((r >> TBIT) & 1) == 0) {
                int r1 = r | (1 << TBIT);
                float2 t0 = amp[r], t1 = amp[r1];
                amp[r]  = c ? t1 : t0;
                amp[r1] = c ? t0 : t1;
            }
    } else if constexpr (CBIT < 3 && TBIT >= 3) {
        // reg control, lane target: shuffle only the controlled regs (uniform flow)
#pragma unroll
        for (int r = 0; r < 8; r++)
            if (((r >> CBIT) & 1) == 1) {
                amp[r] = shflx(amp[r], 1 << (TBIT - 3));
            }
    } else {
        // lane control, lane target
        bool c = (lane >> (CBIT - 3)) & 1;
#pragma unroll
        for (int r = 0; r < 8; r++) {
            float2 o = shflx(amp[r], 1 << (TBIT - 3));
            amp[r] = c ? o : amp[r];
        }
    }
}

// StronglyEntanglingLayers, L=1, 3 wires; gm = 3 precomputed Rot matrices
template <int W0, int W1, int W2>
__device__ __forceinline__ void sel3m(const float* __restrict__ gm, float2 (&amp)[8], int lane) {
    rot1<W0>(ldm(gm),      amp, lane);
    rot1<W1>(ldm(gm + 8),  amp, lane);
    rot1<W2>(ldm(gm + 16), amp, lane);
    cnotg<W0, W1>(amp, lane);
    cnotg<W1, W2>(amp, lane);
    cnotg<W2, W0>(amp, lane);
}

template <int I>
__device__ __forceinline__ void block_i(float2 (&amp)[8], const M4& crx, const M4& cry1,
                                        const M4& crz, const M4& cry2,
                                        const float* __restrict__ gm, int lane) {
    constexpr int EW = I, NB = 4 + I;
    crot<NB, 7>(crx,  amp, lane);
    crot<EW, 7>(cry1, amp, lane);
    crot<NB, 8>(crz,  amp, lane);
    crot<EW, 8>(cry2, amp, lane);
    sel3m<EW, NB, 7>(gm + 32, amp, lane);   // strong[0]
    sel3m<7, NB, 8>(gm + 56,  amp, lane);   // strong[1]
}

// ---------- kernels ----------

// precompute the 13 sample-independent gate matrices into gm (13 x 8 floats):
// [0..3]   crx(inits0), cry(inits1), crz(inits2), cry(inits3)
// [4..6]   strong[0] Rot matrices     (gm floats 32..55)
// [7..9]   strong[1] Rot matrices     (gm floats 56..79)
// [10..12] update Rot matrices        (gm floats 80..103)
__global__ void prep_kernel(const float* __restrict__ strong, const float* __restrict__ inits,
                            const float* __restrict__ update, float* __restrict__ gm) {
    int j = threadIdx.x;
    if (j >= 13) return;
    M4 M;
    if (j == 0)      M = mrx(inits[0]);
    else if (j == 1) M = mry(inits[1]);
    else if (j == 2) M = mrz(inits[2]);
    else if (j == 3) M = mry(inits[3]);
    else if (j < 7)  { const float* w = strong + (j - 4) * 3;     M = mrot(w[0], w[1], w[2]); }
    else if (j < 10) { const float* w = strong + 9 + (j - 7) * 3; M = mrot(w[0], w[1], w[2]); }
    else             { const float* w = update + (j - 10) * 3;    M = mrot(w[0], w[1], w[2]); }
    float* o = gm + j * 8;
    o[0] = M.u00.x; o[1] = M.u00.y; o[2] = M.u01.x; o[3] = M.u01.y;
    o[4] = M.u10.x; o[5] = M.u10.y; o[6] = M.u11.x; o[7] = M.u11.y;
}

// fused node+edge MLP: tanh(mlp(feat))*pi. Blocks [0,nodeBlocks) do nodes
// (IN=8), the rest do edges (IN=4). Branch is block-uniform.
__global__ __launch_bounds__(256) void mlp_both_kernel(
        const float* __restrict__ node_feat, const float* __restrict__ edge_attr,
        const float* __restrict__ Wn1, const float* __restrict__ bn1,
        const float* __restrict__ Wn2, const float* __restrict__ bn2,
        const float* __restrict__ We1, const float* __restrict__ be1,
        const float* __restrict__ We2, const float* __restrict__ be2,
        float* __restrict__ x, float* __restrict__ e,
        int N, int NE, int nodeBlocks) {
    if ((int)blockIdx.x < nodeBlocks) {
        int r = blockIdx.x * 256 + threadIdx.x;
        if (r >= N) return;
        float f[8];
#pragma unroll
        for (int k = 0; k < 8; k++) f[k] = node_feat[r * 8 + k];
        float o0 = bn2[0], o1 = bn2[1];
        for (int j = 0; j < 128; j++) {
            float h = bn1[j];
#pragma unroll
            for (int k = 0; k < 8; k++) h += f[k] * Wn1[k * 128 + j];
            h = h > 0.f ? h : 0.01f * h;
            o0 += h * Wn2[j * 2 + 0];
            o1 += h * Wn2[j * 2 + 1];
        }
        x[r * 2 + 0] = tanhf(o0) * PI_F;
        x[r * 2 + 1] = tanhf(o1) * PI_F;
    } else {
        int r = (blockIdx.x - nodeBlocks) * 256 + threadIdx.x;
        if (r >= NE) return;
        float f[4];
#pragma unroll
        for (int k = 0; k < 4; k++) f[k] = edge_attr[r * 4 + k];
        float o0 = be2[0], o1 = be2[1];
        for (int j = 0; j < 128; j++) {
            float h = be1[j];
#pragma unroll
            for (int k = 0; k < 4; k++) h += f[k] * We1[k * 128 + j];
            h = h > 0.f ? h : 0.01f * h;
            o0 += h * We2[j * 2 + 0];
            o1 += h * We2[j * 2 + 1];
        }
        e[r * 2 + 0] = tanhf(o0) * PI_F;
        e[r * 2 + 1] = tanhf(o1) * PI_F;
    }
}

// 4 samples per 256-thread block, one wave per sample; statevector in registers;
// all shared gate matrices preloaded from gm (wave-uniform scalar loads).
__global__ __launch_bounds__(256) void pqc_kernel(
        const float* __restrict__ x, const float* __restrict__ e,
        const int* __restrict__ subgraphs, const int* __restrict__ edge_ids,
        const float* __restrict__ gm, float* __restrict__ aggr, int ntot) {
    int wave = threadIdx.x >> 6;
    int lane = threadIdx.x & 63;
    int s = blockIdx.x * 4 + wave;
    if (s >= ntot) return;   // wave-uniform

    // angles: rows 0..2 = e[edge_ids[s]], rows 3..6 = x[subgraphs[s]]
    float ang[7][2];
    for (int j = 0; j < 3; j++) {
        int eid = edge_ids[s * 3 + j];
        ang[j][0] = e[2 * eid]; ang[j][1] = e[2 * eid + 1];
    }
    for (int j = 0; j < 4; j++) {
        int nid = subgraphs[s * 4 + j];
        ang[3 + j][0] = x[2 * nid]; ang[3 + j][1] = x[2 * nid + 1];
    }

    // Encoding layer acts on |0..0> -> product state, computed in closed form.
    // v_w = [cos(a/2) e^{-ib/2}, sin(a/2) e^{+ib/2}]. Half-angles are in
    // [-pi/2, pi/2] (angles are tanh*pi) -> native trig is accurate enough.
    float2 c = make_float2(1.f, 0.f);
#pragma unroll
    for (int w = 0; w < 6; w++) {
        float a = 0.5f * ang[w][0], b = 0.5f * ang[w][1];
        float ca = __cosf(a), sa = __sinf(a);
        float cb = __cosf(b), sb = __sinf(b);
        float2 v0 = make_float2(ca * cb, -ca * sb);
        float2 v1 = make_float2(sa * cb,  sa * sb);
        int bit = (lane >> (5 - w)) & 1;
        c = cmul2(c, bit ? v1 : v0);
    }
    float2 amp[8];
#pragma unroll
    for (int r = 0; r < 8; r++) amp[r] = make_float2(0.f, 0.f);
    {
        float a = 0.5f * ang[6][0], b = 0.5f * ang[6][1];
        float ca = __cosf(a), sa = __sinf(a);
        float cb = __cosf(b), sb = __sinf(b);
        amp[0] = cmul2(c, make_float2(ca * cb, -ca * sb));  // wire6=0 (reg bit 2)
        amp[4] = cmul2(c, make_float2(sa * cb,  sa * sb));  // wire6=1
    }

    M4 crx  = ldm(gm);
    M4 cry1 = ldm(gm + 8);
    M4 crz  = ldm(gm + 16);
    M4 cry2 = ldm(gm + 24);

    block_i<0>(amp, crx, cry1, crz, cry2, gm, lane);
    block_i<1>(amp, crx, cry1, crz, cry2, gm, lane);
    block_i<2>(amp, crx, cry1, crz, cry2, gm, lane);
    sel3m<3, 7, 8>(gm + 80, amp, lane);

    // <X_3>: wire 3 -> idx bit 5 -> lane bit 2. Each pair counted from both
    // sides => full-lane sum already equals 2 * sum_over_pairs.
    float acc = 0.f;
#pragma unroll
    for (int r = 0; r < 8; r++) {
        float2 o = shflx(amp[r], 4);
        acc += amp[r].x * o.x + amp[r].y * o.y;
    }
    for (int off = 32; off > 0; off >>= 1) acc += __shfl_down(acc, off, 64);
    if (lane == 0) aggr[s] = acc;
}

// upd = mlp([x[center], aggr], 3->128->2); scatter-add into xadd at center
__global__ void upd_kernel(const float* __restrict__ x, const float* __restrict__ aggr,
                           const int* __restrict__ subgraphs,
                           const float* __restrict__ W1, const float* __restrict__ b1,
                           const float* __restrict__ W2, const float* __restrict__ b2,
                           float* __restrict__ xadd, int rows) {
    int r = blockIdx.x * blockDim.x + threadIdx.x;
    if (r >= rows) return;
    int c = subgraphs[r * 4];
    float f0 = x[2 * c], f1 = x[2 * c + 1], f2 = aggr[r];
    float o0 = b2[0], o1 = b2[1];
    for (int j = 0; j < 128; j++) {
        float h = b1[j] + f0 * W1[j] + f1 * W1[128 + j] + f2 * W1[256 + j];
        h = h > 0.f ? h : 0.01f * h;
        o0 += h * W2[j * 2 + 0];
        o1 += h * W2[j * 2 + 1];
    }
    atomicAdd(&xadd[2 * c + 0], o0);
    atomicAdd(&xadd[2 * c + 1], o1);
}

// segment sum/count per graph — hierarchical: wave shuffle -> LDS bins -> one
// global atomic per bin per block.
#define MAX_GRAPHS 64
__global__ __launch_bounds__(256) void pool_kernel(
        const float* __restrict__ x, const float* __restrict__ xadd,
        const int* __restrict__ batch,
        float* __restrict__ gsum, float* __restrict__ gcnt, int rows, int ngraphs) {
    __shared__ float bins[3 * MAX_GRAPHS];
    for (int i = threadIdx.x; i < 3 * ngraphs; i += blockDim.x) bins[i] = 0.f;
    __syncthreads();

    int r = blockIdx.x * blockDim.x + threadIdx.x;
    int lane = threadIdx.x & 63;
    bool active = r < rows;
    int b = 0; float v0 = 0.f, v1 = 0.f, cc = 0.f;
    if (active) {
        b = batch[r];
        v0 = x[2 * r + 0] + xadd[2 * r + 0];
        v1 = x[2 * r + 1] + xadd[2 * r + 1];
        cc = 1.f;
    }
    int b0 = __shfl(b, 0);
    bool uni = __all(active && b == b0);
    if (uni) {
        for (int off = 32; off > 0; off >>= 1) {
            v0 += __shfl_down(v0, off);
            v1 += __shfl_down(v1, off);
        }
        if (lane == 0) {
            atomicAdd(&bins[3 * b0 + 0], v0);
            atomicAdd(&bins[3 * b0 + 1], v1);
            atomicAdd(&bins[3 * b0 + 2], 64.f);
        }
    } else if (active) {
        atomicAdd(&bins[3 * b + 0], v0);
        atomicAdd(&bins[3 * b + 1], v1);
        atomicAdd(&bins[3 * b + 2], cc);
    }
    __syncthreads();

    for (int i = threadIdx.x; i < ngraphs; i += blockDim.x) {
        float s0 = bins[3 * i + 0], s1 = bins[3 * i + 1], sc = bins[3 * i + 2];
        if (s0 != 0.f || s1 != 0.f || sc != 0.f) {
            atomicAdd(&gsum[2 * i + 0], s0);
            atomicAdd(&gsum[2 * i + 1], s1);
            atomicAdd(&gcnt[i], sc);
        }
    }
}

// g = gsum/gcnt; out = mlp(g, 2->2->2)
__global__ void head_kernel(const float* __restrict__ gsum, const float* __restrict__ gcnt,
                            const float* __restrict__ Wh1, const float* __restrict__ bh1,
                            const float* __restrict__ Wh2, const float* __restrict__ bh2,
                            float* __restrict__ out, int ngraphs) {
    int g = threadIdx.x;
    if (g >= ngraphs) return;
    float c = gcnt[g];
    float g0 = gsum[2 * g + 0] / c;
    float g1 = gsum[2 * g + 1] / c;
    float h0 = g0 * Wh1[0] + g1 * Wh1[2] + bh1[0];
    float h1 = g0 * Wh1[1] + g1 * Wh1[3] + bh1[1];
    h0 = h0 > 0.f ? h0 : 0.01f * h0;
    h1 = h1 > 0.f ? h1 : 0.01f * h1;
    out[2 * g + 0] = h0 * Wh2[0] + h1 * Wh2[2] + bh2[0];
    out[2 * g + 1] = h0 * Wh2[1] + h1 * Wh2[3] + bh2[1];
}

extern "C" void kernel_launch(void* const* d_in, const int* in_sizes, int n_in,
                              void* d_out, int out_size, void* d_ws, size_t ws_size,
                              hipStream_t stream) {
    const float* node_feat = (const float*)d_in[0];   // (N, 8)
    const float* edge_attr = (const float*)d_in[1];   // (3N, 4)
    const float* Wn1 = (const float*)d_in[2];
    const float* bn1 = (const float*)d_in[3];
    const float* Wn2 = (const float*)d_in[4];
    const float* bn2 = (const float*)d_in[5];
    const float* We1 = (const float*)d_in[6];
    const float* be1 = (const float*)d_in[7];
    const float* We2 = (const float*)d_in[8];
    const float* be2 = (const float*)d_in[9];
    const float* strong = (const float*)d_in[10];     // (2,1,3,3)
    const float* inits  = (const float*)d_in[11];     // (1,4)
    const float* update = (const float*)d_in[12];     // (1,3,3)
    const float* Wu1 = (const float*)d_in[13];
    const float* bu1 = (const float*)d_in[14];
    const float* Wu2 = (const float*)d_in[15];
    const float* bu2 = (const float*)d_in[16];
    const float* Wh1 = (const float*)d_in[17];
    const float* bh1 = (const float*)d_in[18];
    const float* Wh2 = (const float*)d_in[19];
    const float* bh2 = (const float*)d_in[20];
    const int* subgraphs = (const int*)d_in[21];      // (N, 4)
    const int* edge_ids  = (const int*)d_in[22];      // (N, 3)
    const int* batch     = (const int*)d_in[23];      // (N,)

    const int N  = in_sizes[0] / 8;      // 4096 nodes
    const int NE = in_sizes[1] / 4;      // 12288 edges
    const int NG = out_size / 2;         // 16 graphs

    // workspace layout (floats)
    float* ws   = (float*)d_ws;
    float* x    = ws;                    // N*2
    float* e    = x + (size_t)N * 2;     // NE*2
    float* aggr = e + (size_t)NE * 2;    // N
    float* xadd = aggr + N;              // N*2
    float* gsum = xadd + (size_t)N * 2;  // NG*2
    float* gcnt = gsum + (size_t)NG * 2; // NG
    float* gm   = gcnt + NG;             // 13*8 = 104 floats of gate matrices

    // zero the accumulator region (xadd, gsum, gcnt)
    hipMemsetAsync(xadd, 0, (size_t)(N * 2 + NG * 3) * sizeof(float), stream);

    prep_kernel<<<1, 64, 0, stream>>>(strong, inits, update, gm);

    int nodeBlocks = (N + 255) / 256;
    int edgeBlocks = (NE + 255) / 256;
    mlp_both_kernel<<<nodeBlocks + edgeBlocks, 256, 0, stream>>>(
        node_feat, edge_attr, Wn1, bn1, Wn2, bn2, We1, be1, We2, be2, x, e, N, NE, nodeBlocks);

    pqc_kernel<<<(N + 3) / 4, 256, 0, stream>>>(x, e, subgraphs, edge_ids, gm, aggr, N);

    upd_kernel<<<(N + 255) / 256, 256, 0, stream>>>(x, aggr, subgraphs, Wu1, bu1, Wu2, bu2, xadd, N);
    pool_kernel<<<(N + 255) / 256, 256, 0, stream>>>(x, xadd, batch, gsum, gcnt, N, NG);
    head_kernel<<<1, 64, 0, stream>>>(gsum, gcnt, Wh1, bh1, Wh2, bh2, (float*)d_out, NG);
}

// Round 5
// 151.246 us; speedup vs baseline: 2.0077x; 1.0756x over previous
//
#include <hip/hip_runtime.h>
#include <math.h>

#define PI_F 3.14159265358979323846f

// ---------- complex helpers (float2 as complex) ----------
__device__ __forceinline__ float2 cmul2(float2 a, float2 b) {
    return make_float2(a.x * b.x - a.y * b.y, a.x * b.y + a.y * b.x);
}
// u*a + v*b
__device__ __forceinline__ float2 cmac2(float2 u, float2 a, float2 v, float2 b) {
    float2 r;
    r.x = u.x * a.x - u.y * a.y + v.x * b.x - v.y * b.y;
    r.y = u.x * a.y + u.y * a.x + v.x * b.y + v.y * b.x;
    return r;
}

struct M4 { float2 u00, u01, u10, u11; };

__device__ __forceinline__ M4 mmul4(const M4& A, const M4& B) {
    M4 R;
    R.u00 = cmac2(A.u00, B.u00, A.u01, B.u10);
    R.u01 = cmac2(A.u00, B.u01, A.u01, B.u11);
    R.u10 = cmac2(A.u10, B.u00, A.u11, B.u10);
    R.u11 = cmac2(A.u10, B.u01, A.u11, B.u11);
    return R;
}
__device__ __forceinline__ M4 mry(float t) {
    float c = cosf(0.5f * t), s = sinf(0.5f * t);
    M4 R; R.u00 = {c, 0}; R.u01 = {-s, 0}; R.u10 = {s, 0}; R.u11 = {c, 0};
    return R;
}
__device__ __forceinline__ M4 mrz(float t) {
    float c = cosf(0.5f * t), s = sinf(0.5f * t);
    M4 R; R.u00 = {c, -s}; R.u01 = {0, 0}; R.u10 = {0, 0}; R.u11 = {c, s};
    return R;
}
// Rot(phi, theta, omega) = RZ(omega) @ RY(theta) @ RZ(phi)
__device__ __forceinline__ M4 mrot(float phi, float th, float om) {
    return mmul4(mmul4(mrz(om), mry(th)), mrz(phi));
}

__device__ __forceinline__ float2 shflx(float2 v, int mask) {
    return make_float2(__shfl_xor(v.x, mask, 64), __shfl_xor(v.y, mask, 64));
}

// load an M4 from wave-uniform global memory (compiler emits scalar loads)
__device__ __forceinline__ M4 ldm(const float* __restrict__ g) {
    M4 M;
    M.u00 = make_float2(g[0], g[1]); M.u01 = make_float2(g[2], g[3]);
    M.u10 = make_float2(g[4], g[5]); M.u11 = make_float2(g[6], g[7]);
    return M;
}

// ---------- register statevector: idx = lane*8 + r ----------
// idx bit b: b in [0,2] -> register bit b; b in [3,8] -> lane bit (b-3).
// wire w -> idx bit (8-w). Wires 0..5 = lane bits 5..0; wires 6,7,8 = reg bits 2,1,0.

// single-qubit dense gate on register bit TB
template <int TB>
__device__ __forceinline__ void rot_reg(const M4& U, float2 (&amp)[8]) {
#pragma unroll
    for (int r = 0; r < 8; r++)
        if (((r >> TB) & 1) == 0) {
            int r1 = r | (1 << TB);
            float2 a = amp[r], b = amp[r1];
            amp[r]  = cmac2(U.u00, a, U.u01, b);
            amp[r1] = cmac2(U.u10, a, U.u11, b);
        }
}

// single-qubit dense gate on lane bit LB
template <int LB>
__device__ __forceinline__ void rot_lane(const M4& U, float2 (&amp)[8], int lane) {
    bool hi = (lane >> LB) & 1;
    float2 cA = hi ? U.u11 : U.u00;
    float2 cB = hi ? U.u10 : U.u01;
#pragma unroll
    for (int r = 0; r < 8; r++) {
        float2 o = shflx(amp[r], 1 << LB);
        amp[r] = cmac2(cA, amp[r], cB, o);
    }
}

template <int WIRE>
__device__ __forceinline__ void rot1(const M4& U, float2 (&amp)[8], int lane) {
    constexpr int BIT = 8 - WIRE;
    if constexpr (BIT < 3) rot_reg<BIT>(U, amp);
    else rot_lane<BIT - 3>(U, amp, lane);
}

// ---------- specialized controlled rotations (target = reg bit TB) ----------
// CBIT = index bit of the control wire. Lane-control folds to identity via
// (c,s)->(1,0) select; reg-control restricts the pair set at compile time.

// controlled RX: [[c, -i s], [-i s, c]]
template <int CBIT, int TB>
__device__ __forceinline__ void crx_g(float c, float s, float2 (&amp)[8], int lane) {
    if constexpr (CBIT >= 3) {
        bool ct = (lane >> (CBIT - 3)) & 1;
        float cc = ct ? c : 1.f, ss = ct ? s : 0.f;
#pragma unroll
        for (int r = 0; r < 8; r++)
            if (((r >> TB) & 1) == 0) {
                int r1 = r | (1 << TB);
                float2 a = amp[r], b = amp[r1];
                amp[r]  = make_float2(cc * a.x + ss * b.y, cc * a.y - ss * b.x);
                amp[r1] = make_float2(ss * a.y + cc * b.x, cc * b.y - ss * a.x);
            }
    } else {
#pragma unroll
        for (int r = 0; r < 8; r++)
            if (((r >> CBIT) & 1) == 1 && ((r >> TB) & 1) == 0) {
                int r1 = r | (1 << TB);
                float2 a = amp[r], b = amp[r1];
                amp[r]  = make_float2(c * a.x + s * b.y, c * a.y - s * b.x);
                amp[r1] = make_float2(s * a.y + c * b.x, c * b.y - s * a.x);
            }
    }
}

// controlled RY: [[c, -s], [s, c]] (real)
template <int CBIT, int TB>
__device__ __forceinline__ void cry_g(float c, float s, float2 (&amp)[8], int lane) {
    if constexpr (CBIT >= 3) {
        bool ct = (lane >> (CBIT - 3)) & 1;
        float cc = ct ? c : 1.f, ss = ct ? s : 0.f;
#pragma unroll
        for (int r = 0; r < 8; r++)
            if (((r >> TB) & 1) == 0) {
                int r1 = r | (1 << TB);
                float2 a = amp[r], b = amp[r1];
                amp[r]  = make_float2(cc * a.x - ss * b.x, cc * a.y - ss * b.y);
                amp[r1] = make_float2(ss * a.x + cc * b.x, ss * a.y + cc * b.y);
            }
    } else {
#pragma unroll
        for (int r = 0; r < 8; r++)
            if (((r >> CBIT) & 1) == 1 && ((r >> TB) & 1) == 0) {
                int r1 = r | (1 << TB);
                float2 a = amp[r], b = amp[r1];
                amp[r]  = make_float2(c * a.x - s * b.x, c * a.y - s * b.y);
                amp[r1] = make_float2(s * a.x + c * b.x, s * a.y + c * b.y);
            }
    }
}

// controlled RZ: diag(e, conj(e)), e = c - i s
template <int CBIT, int TB>
__device__ __forceinline__ void crz_g(float c, float s, float2 (&amp)[8], int lane) {
    if constexpr (CBIT >= 3) {
        bool ct = (lane >> (CBIT - 3)) & 1;
        float cc = ct ? c : 1.f, ss = ct ? s : 0.f;
#pragma unroll
        for (int r = 0; r < 8; r++)
            if (((r >> TB) & 1) == 0) {
                int r1 = r | (1 << TB);
                float2 a = amp[r], b = amp[r1];
                amp[r]  = make_float2(cc * a.x + ss * a.y, cc * a.y - ss * a.x);
                amp[r1] = make_float2(cc * b.x - ss * b.y, cc * b.y + ss * b.x);
            }
    } else {
#pragma unroll
        for (int r = 0; r < 8; r++)
            if (((r >> CBIT) & 1) == 1 && ((r >> TB) & 1) == 0) {
                int r1 = r | (1 << TB);
                float2 a = amp[r], b = amp[r1];
                amp[r]  = make_float2(c * a.x + s * a.y, c * a.y - s * a.x);
                amp[r1] = make_float2(c * b.x - s * b.y, c * b.y + s * b.x);
            }
    }
}

template <int CW, int TW>
__device__ __forceinline__ void cnotg(float2 (&amp)[8], int lane) {
    constexpr int CBIT = 8 - CW, TBIT = 8 - TW;
    if constexpr (CBIT < 3 && TBIT < 3) {
        // reg control, reg target: conditional register swap
#pragma unroll
        for (int r = 0; r < 8; r++)
            if (((r >> CBIT) & 1) == 1 && ((r >> TBIT) & 1) == 0) {
                int r1 = r | (1 << TBIT);
                float2 t = amp[r]; amp[r] = amp[r1]; amp[r1] = t;
            }
    } else if constexpr (CBIT >= 3 && TBIT < 3) {
        // lane control, reg target: per-lane select
        bool c = (lane >> (CBIT - 3)) & 1;
#pragma unroll
        for (int r = 0; r < 8; r++)
            if (((r >> TBIT) & 1) == 0) {
                int r1 = r | (1 << TBIT);
                float2 t0 = amp[r], t1 = amp[r1];
                amp[r]  = c ? t1 : t0;
                amp[r1] = c ? t0 : t1;
            }
    } else if constexpr (CBIT < 3 && TBIT >= 3) {
        // reg control, lane target: shuffle only the controlled regs (uniform flow)
#pragma unroll
        for (int r = 0; r < 8; r++)
            if (((r >> CBIT) & 1) == 1) {
                amp[r] = shflx(amp[r], 1 << (TBIT - 3));
            }
    } else {
        // lane control, lane target
        bool c = (lane >> (CBIT - 3)) & 1;
#pragma unroll
        for (int r = 0; r < 8; r++) {
            float2 o = shflx(amp[r], 1 << (TBIT - 3));
            amp[r] = c ? o : amp[r];
        }
    }
}

// StronglyEntanglingLayers, L=1, 3 wires; gm = 3 precomputed dense Rot matrices
template <int W0, int W1, int W2>
__device__ __forceinline__ void sel3m(const float* __restrict__ gm, float2 (&amp)[8], int lane) {
    rot1<W0>(ldm(gm),      amp, lane);
    rot1<W1>(ldm(gm + 8),  amp, lane);
    rot1<W2>(ldm(gm + 16), amp, lane);
    cnotg<W0, W1>(amp, lane);
    cnotg<W1, W2>(amp, lane);
    cnotg<W2, W0>(amp, lane);
}

// gm layout (floats):
// [0..7]  (c,s) for crx, cry1, crz, cry2
// [8..31]   strong[0] 3 dense Rot M4s
// [32..55]  strong[1]
// [56..79]  update
template <int I>
__device__ __forceinline__ void block_i(float2 (&amp)[8], float cx, float sx, float cy1, float sy1,
                                        float cz, float sz, float cy2, float sy2,
                                        const float* __restrict__ gm, int lane) {
    // wires: EW = I (bit 8-I, lane), NB = 4+I (bit 4-I), a1 = 7 (reg bit 1), a2 = 8 (reg bit 0)
    crx_g<4 - I, 1>(cx,  sx,  amp, lane);
    cry_g<8 - I, 1>(cy1, sy1, amp, lane);
    crz_g<4 - I, 0>(cz,  sz,  amp, lane);
    cry_g<8 - I, 0>(cy2, sy2, amp, lane);
    sel3m<I, 4 + I, 7>(gm + 8,  amp, lane);   // strong[0]
    sel3m<7, 4 + I, 8>(gm + 32, amp, lane);   // strong[1]
}

// ---------- kernels ----------

// precompute shared gate data into gm; idle lanes zero gsum/gcnt (3*NG floats at zbuf)
__global__ void prep_kernel(const float* __restrict__ strong, const float* __restrict__ inits,
                            const float* __restrict__ update, float* __restrict__ gm,
                            float* __restrict__ zbuf, int nzero) {
    int j = threadIdx.x;
    if (j < 4) {
        gm[2 * j]     = cosf(0.5f * inits[j]);
        gm[2 * j + 1] = sinf(0.5f * inits[j]);
    } else if (j < 13) {
        const float* w;
        if (j < 7)       w = strong + (j - 4) * 3;
        else if (j < 10) w = strong + 9 + (j - 7) * 3;
        else             w = update + (j - 10) * 3;
        M4 M = mrot(w[0], w[1], w[2]);
        float* o = gm + 8 + (j - 4) * 8;
        o[0] = M.u00.x; o[1] = M.u00.y; o[2] = M.u01.x; o[3] = M.u01.y;
        o[4] = M.u10.x; o[5] = M.u10.y; o[6] = M.u11.x; o[7] = M.u11.y;
    }
    for (int i = j; i < nzero; i += 64) zbuf[i] = 0.f;
}

// fused node+edge MLP: tanh(mlp(feat))*pi. Blocks [0,nodeBlocks) do nodes
// (IN=8), the rest do edges (IN=4). Branch is block-uniform.
__global__ __launch_bounds__(256) void mlp_both_kernel(
        const float* __restrict__ node_feat, const float* __restrict__ edge_attr,
        const float* __restrict__ Wn1, const float* __restrict__ bn1,
        const float* __restrict__ Wn2, const float* __restrict__ bn2,
        const float* __restrict__ We1, const float* __restrict__ be1,
        const float* __restrict__ We2, const float* __restrict__ be2,
        float* __restrict__ x, float* __restrict__ e,
        int N, int NE, int nodeBlocks) {
    if ((int)blockIdx.x < nodeBlocks) {
        int r = blockIdx.x * 256 + threadIdx.x;
        if (r >= N) return;
        float f[8];
#pragma unroll
        for (int k = 0; k < 8; k++) f[k] = node_feat[r * 8 + k];
        float o0 = bn2[0], o1 = bn2[1];
        for (int j = 0; j < 128; j++) {
            float h = bn1[j];
#pragma unroll
            for (int k = 0; k < 8; k++) h += f[k] * Wn1[k * 128 + j];
            h = h > 0.f ? h : 0.01f * h;
            o0 += h * Wn2[j * 2 + 0];
            o1 += h * Wn2[j * 2 + 1];
        }
        x[r * 2 + 0] = tanhf(o0) * PI_F;
        x[r * 2 + 1] = tanhf(o1) * PI_F;
    } else {
        int r = (blockIdx.x - nodeBlocks) * 256 + threadIdx.x;
        if (r >= NE) return;
        float f[4];
#pragma unroll
        for (int k = 0; k < 4; k++) f[k] = edge_attr[r * 4 + k];
        float o0 = be2[0], o1 = be2[1];
        for (int j = 0; j < 128; j++) {
            float h = be1[j];
#pragma unroll
            for (int k = 0; k < 4; k++) h += f[k] * We1[k * 128 + j];
            h = h > 0.f ? h : 0.01f * h;
            o0 += h * We2[j * 2 + 0];
            o1 += h * We2[j * 2 + 1];
        }
        e[r * 2 + 0] = tanhf(o0) * PI_F;
        e[r * 2 + 1] = tanhf(o1) * PI_F;
    }
}

// 4 samples per 256-thread block, one wave per sample; statevector in registers;
// all shared gate data preloaded from gm (wave-uniform scalar loads).
__global__ __launch_bounds__(256) void pqc_kernel(
        const float* __restrict__ x, const float* __restrict__ e,
        const int* __restrict__ subgraphs, const int* __restrict__ edge_ids,
        const float* __restrict__ gm, float* __restrict__ aggr, int ntot) {
    int wave = threadIdx.x >> 6;
    int lane = threadIdx.x & 63;
    int s = blockIdx.x * 4 + wave;
    if (s >= ntot) return;   // wave-uniform

    // angles: rows 0..2 = e[edge_ids[s]], rows 3..6 = x[subgraphs[s]]
    float ang[7][2];
    for (int j = 0; j < 3; j++) {
        int eid = edge_ids[s * 3 + j];
        ang[j][0] = e[2 * eid]; ang[j][1] = e[2 * eid + 1];
    }
    for (int j = 0; j < 4; j++) {
        int nid = subgraphs[s * 4 + j];
        ang[3 + j][0] = x[2 * nid]; ang[3 + j][1] = x[2 * nid + 1];
    }

    // Encoding layer acts on |0..0> -> product state, computed in closed form.
    // v_w = [cos(a/2) e^{-ib/2}, sin(a/2) e^{+ib/2}]. Half-angles in
    // [-pi/2, pi/2] -> native trig is accurate enough.
    float2 c = make_float2(1.f, 0.f);
#pragma unroll
    for (int w = 0; w < 6; w++) {
        float a = 0.5f * ang[w][0], b = 0.5f * ang[w][1];
        float ca = __cosf(a), sa = __sinf(a);
        float cb = __cosf(b), sb = __sinf(b);
        float2 v0 = make_float2(ca * cb, -ca * sb);
        float2 v1 = make_float2(sa * cb,  sa * sb);
        int bit = (lane >> (5 - w)) & 1;
        c = cmul2(c, bit ? v1 : v0);
    }
    float2 amp[8];
#pragma unroll
    for (int r = 0; r < 8; r++) amp[r] = make_float2(0.f, 0.f);
    {
        float a = 0.5f * ang[6][0], b = 0.5f * ang[6][1];
        float ca = __cosf(a), sa = __sinf(a);
        float cb = __cosf(b), sb = __sinf(b);
        amp[0] = cmul2(c, make_float2(ca * cb, -ca * sb));  // wire6=0 (reg bit 2)
        amp[4] = cmul2(c, make_float2(sa * cb,  sa * sb));  // wire6=1
    }

    float cx  = gm[0], sx  = gm[1];
    float cy1 = gm[2], sy1 = gm[3];
    float cz  = gm[4], sz  = gm[5];
    float cy2 = gm[6], sy2 = gm[7];

    block_i<0>(amp, cx, sx, cy1, sy1, cz, sz, cy2, sy2, gm, lane);
    block_i<1>(amp, cx, sx, cy1, sy1, cz, sz, cy2, sy2, gm, lane);
    block_i<2>(amp, cx, sx, cy1, sy1, cz, sz, cy2, sy2, gm, lane);
    sel3m<3, 7, 8>(gm + 56, amp, lane);

    // <X_3>: wire 3 -> idx bit 5 -> lane bit 2. Each pair counted from both
    // sides => full-lane sum already equals 2 * sum_over_pairs.
    float acc = 0.f;
#pragma unroll
    for (int r = 0; r < 8; r++) {
        float2 o = shflx(amp[r], 4);
        acc += amp[r].x * o.x + amp[r].y * o.y;
    }
    for (int off = 32; off > 0; off >>= 1) acc += __shfl_down(acc, off, 64);
    if (lane == 0) aggr[s] = acc;
}

// fused update-MLP + pooling. Thread r contributes:
//   x[r]            -> bin[batch[r]]   (+count)
//   upd(sample r)   -> bin[batch[center_r]]
// gsum is linear, so no xadd scatter buffer / extra pass is needed.
#define MAX_GRAPHS 64
__global__ __launch_bounds__(256) void pool_upd_kernel(
        const float* __restrict__ x, const float* __restrict__ aggr,
        const int* __restrict__ subgraphs, const int* __restrict__ batch,
        const float* __restrict__ W1, const float* __restrict__ b1,
        const float* __restrict__ W2, const float* __restrict__ b2,
        float* __restrict__ gsum, float* __restrict__ gcnt, int rows, int ngraphs) {
    __shared__ float bins[3 * MAX_GRAPHS];
    for (int i = threadIdx.x; i < 3 * ngraphs; i += blockDim.x) bins[i] = 0.f;
    __syncthreads();

    int r = blockIdx.x * blockDim.x + threadIdx.x;
    int lane = threadIdx.x & 63;
    bool active = r < rows;
    int b = 0, bc = 0;
    float v0 = 0.f, v1 = 0.f, o0 = 0.f, o1 = 0.f;
    if (active) {
        b = batch[r];
        v0 = x[2 * r + 0];
        v1 = x[2 * r + 1];
        int cidx = subgraphs[r * 4];
        bc = batch[cidx];
        float f0 = x[2 * cidx], f1 = x[2 * cidx + 1], f2 = aggr[r];
        o0 = b2[0]; o1 = b2[1];
        for (int j = 0; j < 128; j++) {
            float h = b1[j] + f0 * W1[j] + f1 * W1[128 + j] + f2 * W1[256 + j];
            h = h > 0.f ? h : 0.01f * h;
            o0 += h * W2[j * 2 + 0];
            o1 += h * W2[j * 2 + 1];
        }
    }
    int b0 = __shfl(b, 0);
    bool uni = __all(active && b == b0 && bc == b0);
    if (uni) {
        float s0 = v0 + o0, s1 = v1 + o1;
        for (int off = 32; off > 0; off >>= 1) {
            s0 += __shfl_down(s0, off);
            s1 += __shfl_down(s1, off);
        }
        if (lane == 0) {
            atomicAdd(&bins[3 * b0 + 0], s0);
            atomicAdd(&bins[3 * b0 + 1], s1);
            atomicAdd(&bins[3 * b0 + 2], 64.f);
        }
    } else if (active) {
        atomicAdd(&bins[3 * b + 0], v0);
        atomicAdd(&bins[3 * b + 1], v1);
        atomicAdd(&bins[3 * b + 2], 1.f);
        atomicAdd(&bins[3 * bc + 0], o0);
        atomicAdd(&bins[3 * bc + 1], o1);
    }
    __syncthreads();

    for (int i = threadIdx.x; i < ngraphs; i += blockDim.x) {
        float s0 = bins[3 * i + 0], s1 = bins[3 * i + 1], sc = bins[3 * i + 2];
        if (s0 != 0.f || s1 != 0.f || sc != 0.f) {
            atomicAdd(&gsum[2 * i + 0], s0);
            atomicAdd(&gsum[2 * i + 1], s1);
            atomicAdd(&gcnt[i], sc);
        }
    }
}

// g = gsum/gcnt; out = mlp(g, 2->2->2)
__global__ void head_kernel(const float* __restrict__ gsum, const float* __restrict__ gcnt,
                            const float* __restrict__ Wh1, const float* __restrict__ bh1,
                            const float* __restrict__ Wh2, const float* __restrict__ bh2,
                            float* __restrict__ out, int ngraphs) {
    int g = threadIdx.x;
    if (g >= ngraphs) return;
    float c = gcnt[g];
    float g0 = gsum[2 * g + 0] / c;
    float g1 = gsum[2 * g + 1] / c;
    float h0 = g0 * Wh1[0] + g1 * Wh1[2] + bh1[0];
    float h1 = g0 * Wh1[1] + g1 * Wh1[3] + bh1[1];
    h0 = h0 > 0.f ? h0 : 0.01f * h0;
    h1 = h1 > 0.f ? h1 : 0.01f * h1;
    out[2 * g + 0] = h0 * Wh2[0] + h1 * Wh2[2] + bh2[0];
    out[2 * g + 1] = h0 * Wh2[1] + h1 * Wh2[3] + bh2[1];
}

extern "C" void kernel_launch(void* const* d_in, const int* in_sizes, int n_in,
                              void* d_out, int out_size, void* d_ws, size_t ws_size,
                              hipStream_t stream) {
    const float* node_feat = (const float*)d_in[0];   // (N, 8)
    const float* edge_attr = (const float*)d_in[1];   // (3N, 4)
    const float* Wn1 = (const float*)d_in[2];
    const float* bn1 = (const float*)d_in[3];
    const float* Wn2 = (const float*)d_in[4];
    const float* bn2 = (const float*)d_in[5];
    const float* We1 = (const float*)d_in[6];
    const float* be1 = (const float*)d_in[7];
    const float* We2 = (const float*)d_in[8];
    const float* be2 = (const float*)d_in[9];
    const float* strong = (const float*)d_in[10];     // (2,1,3,3)
    const float* inits  = (const float*)d_in[11];     // (1,4)
    const float* update = (const float*)d_in[12];     // (1,3,3)
    const float* Wu1 = (const float*)d_in[13];
    const float* bu1 = (const float*)d_in[14];
    const float* Wu2 = (const float*)d_in[15];
    const float* bu2 = (const float*)d_in[16];
    const float* Wh1 = (const float*)d_in[17];
    const float* bh1 = (const float*)d_in[18];
    const float* Wh2 = (const float*)d_in[19];
    const float* bh2 = (const float*)d_in[20];
    const int* subgraphs = (const int*)d_in[21];      // (N, 4)
    const int* edge_ids  = (const int*)d_in[22];      // (N, 3)
    const int* batch     = (const int*)d_in[23];      // (N,)

    const int N  = in_sizes[0] / 8;      // 4096 nodes
    const int NE = in_sizes[1] / 4;      // 12288 edges
    const int NG = out_size / 2;         // 16 graphs

    // workspace layout (floats)
    float* ws   = (float*)d_ws;
    float* x    = ws;                    // N*2
    float* e    = x + (size_t)N * 2;     // NE*2
    float* aggr = e + (size_t)NE * 2;    // N
    float* gsum = aggr + N;              // NG*2
    float* gcnt = gsum + (size_t)NG * 2; // NG      (contiguous with gsum)
    float* gm   = gcnt + NG;             // 80 floats of gate data

    // prep also zeroes gsum+gcnt (3*NG floats, contiguous)
    prep_kernel<<<1, 64, 0, stream>>>(strong, inits, update, gm, gsum, 3 * NG);

    int nodeBlocks = (N + 255) / 256;
    int edgeBlocks = (NE + 255) / 256;
    mlp_both_kernel<<<nodeBlocks + edgeBlocks, 256, 0, stream>>>(
        node_feat, edge_attr, Wn1, bn1, Wn2, bn2, We1, be1, We2, be2, x, e, N, NE, nodeBlocks);

    pqc_kernel<<<(N + 3) / 4, 256, 0, stream>>>(x, e, subgraphs, edge_ids, gm, aggr, N);

    pool_upd_kernel<<<(N + 255) / 256, 256, 0, stream>>>(
        x, aggr, subgraphs, batch, Wu1, bu1, Wu2, bu2, gsum, gcnt, N, NG);

    head_kernel<<<1, 64, 0, stream>>>(gsum, gcnt, Wh1, bh1, Wh2, bh2, (float*)d_out, NG);
}